// Round 1
// baseline (6374.211 us; speedup 1.0000x reference)
//
#include <hip/hip_runtime.h>

typedef __bf16 bf16_t;
typedef __bf16 bf16x8 __attribute__((ext_vector_type(8)));
typedef __bf16 bf16x4 __attribute__((ext_vector_type(4)));
typedef float  f32x4  __attribute__((ext_vector_type(4)));

// ---------------- f32 -> bf16 cast ----------------
__global__ __launch_bounds__(256) void cast_bf16_kernel(const float* __restrict__ in,
                                                        bf16_t* __restrict__ out, int n4) {
    int i = blockIdx.x * 256 + threadIdx.x;
    if (i >= n4) return;
    f32x4 v = *reinterpret_cast<const f32x4*>(in + (size_t)i * 4);
    bf16x4 o;
    o[0] = (bf16_t)v[0]; o[1] = (bf16_t)v[1]; o[2] = (bf16_t)v[2]; o[3] = (bf16_t)v[3];
    *reinterpret_cast<bf16x4*>(out + (size_t)i * 4) = o;
}

// ---------------- C = A (MxK, row-major) * B^T (B is NxK row-major) ----------------
// 128x128 block tile, BK=32, 256 threads (4 waves, 2x2), each wave 64x64 via 4x4 MFMA 16x16x32.
template <int OUT_BF16>
__global__ __launch_bounds__(256) void gemm_bt(const bf16_t* __restrict__ A,
                                               const bf16_t* __restrict__ Bm,
                                               void* __restrict__ Cv,
                                               int M, int N, int K) {
    __shared__ bf16_t As[128 * 32];
    __shared__ bf16_t Bs[128 * 32];
    const int nbn = N >> 7;
    const int nwg = (M >> 7) * nbn;
    int bid = blockIdx.x;
    int swz = ((nwg & 7) == 0) ? ((bid & 7) * (nwg >> 3) + (bid >> 3)) : bid;
    int bm = swz / nbn, bn = swz % nbn;

    int tid = threadIdx.x;
    int w = tid >> 6, lane = tid & 63;
    int wm = w >> 1, wn = w & 1;
    int lrow = lane & 15, lk = lane >> 4;

    int srow = tid >> 1;             // 0..127
    int scol = (tid & 1) << 4;       // 0 or 16
    const bf16_t* Ab = A  + (size_t)(bm * 128 + srow) * K + scol;
    const bf16_t* Bb = Bm + (size_t)(bn * 128 + srow) * K + scol;

    f32x4 acc[4][4];
#pragma unroll
    for (int i = 0; i < 4; i++)
#pragma unroll
        for (int j = 0; j < 4; j++) acc[i][j] = (f32x4){0.f, 0.f, 0.f, 0.f};

    for (int k0 = 0; k0 < K; k0 += 32) {
        bf16x8 a0 = *reinterpret_cast<const bf16x8*>(Ab + k0);
        bf16x8 a1 = *reinterpret_cast<const bf16x8*>(Ab + k0 + 8);
        bf16x8 b0 = *reinterpret_cast<const bf16x8*>(Bb + k0);
        bf16x8 b1 = *reinterpret_cast<const bf16x8*>(Bb + k0 + 8);
        __syncthreads();  // protect previous iteration's LDS reads
        *reinterpret_cast<bf16x8*>(&As[srow * 32 + scol])     = a0;
        *reinterpret_cast<bf16x8*>(&As[srow * 32 + scol + 8]) = a1;
        *reinterpret_cast<bf16x8*>(&Bs[srow * 32 + scol])     = b0;
        *reinterpret_cast<bf16x8*>(&Bs[srow * 32 + scol + 8]) = b1;
        __syncthreads();
        bf16x8 af[4], bfr[4];
#pragma unroll
        for (int i = 0; i < 4; i++)
            af[i] = *reinterpret_cast<const bf16x8*>(&As[(wm * 64 + i * 16 + lrow) * 32 + lk * 8]);
#pragma unroll
        for (int i = 0; i < 4; i++)
            bfr[i] = *reinterpret_cast<const bf16x8*>(&Bs[(wn * 64 + i * 16 + lrow) * 32 + lk * 8]);
#pragma unroll
        for (int mi = 0; mi < 4; mi++)
#pragma unroll
            for (int ni = 0; ni < 4; ni++)
                acc[mi][ni] = __builtin_amdgcn_mfma_f32_16x16x32_bf16(af[mi], bfr[ni], acc[mi][ni], 0, 0, 0);
    }

    int row0 = bm * 128 + wm * 64 + lk * 4;
    int colb = bn * 128 + wn * 64 + lrow;
#pragma unroll
    for (int mi = 0; mi < 4; mi++)
#pragma unroll
        for (int ni = 0; ni < 4; ni++)
#pragma unroll
            for (int j = 0; j < 4; j++) {
                size_t idx = (size_t)(row0 + mi * 16 + j) * N + (colb + ni * 16);
                float v = acc[mi][ni][j];
                if (OUT_BF16) reinterpret_cast<bf16_t*>(Cv)[idx] = (bf16_t)v;
                else          reinterpret_cast<float*>(Cv)[idx]  = v;
            }
}

// ---------------- sequential scan over 64 segments, one block per (b,h) ----------------
__global__ __launch_bounds__(256) void infini_scan(const bf16_t* __restrict__ Qb,
                                                   const bf16_t* __restrict__ Kb,
                                                   const bf16_t* __restrict__ Vb,
                                                   const float* __restrict__ beta_param,
                                                   bf16_t* __restrict__ outp,
                                                   float* __restrict__ Mfin,
                                                   float* __restrict__ zfin) {
    const int T = 4096, S = 64;
    __shared__ float  Msh[64 * 68];   // f32 memory state, padded rows (16B-aligned, low-conflict)
    __shared__ float  pT[64 * 68];    // softmax probs, transposed [t][r]
    __shared__ bf16_t kbB[64 * 72];   // k segment, bf16
    __shared__ bf16_t vbB[64 * 72];   // v segment (later overwritten with u = v - V_prev)
    __shared__ float  zsh[64];

    int bh = blockIdx.x;
    int b = bh >> 4, h = bh & 15;
    int tid = threadIdx.x;
    int r = tid >> 2;          // row (or t / k-row role later)
    int qd = tid & 3;          // column quarter
    int c0 = qd << 4;

    float beta = 1.f / (1.f + __expf(-beta_param[h]));
    float omb = 1.f - beta;

    for (int i = tid; i < 64 * 68; i += 256) Msh[i] = 0.f;
    if (tid < 64) zsh[tid] = 0.f;

    size_t base_bh = ((size_t)b * T) * 1024 + (size_t)h * 64;
    float qf[64];
    __syncthreads();

    for (int s = 0; s < S; s++) {
        size_t segbase = base_bh + (size_t)s * 64 * 1024;
        // ---- stage k, v (bf16 copy into LDS) ----
        {
            size_t g = segbase + (size_t)r * 1024 + c0;
            bf16x8 k0 = *reinterpret_cast<const bf16x8*>(Kb + g);
            bf16x8 k1 = *reinterpret_cast<const bf16x8*>(Kb + g + 8);
            bf16x8 v0 = *reinterpret_cast<const bf16x8*>(Vb + g);
            bf16x8 v1 = *reinterpret_cast<const bf16x8*>(Vb + g + 8);
            *reinterpret_cast<bf16x8*>(&kbB[r * 72 + c0])     = k0;
            *reinterpret_cast<bf16x8*>(&kbB[r * 72 + c0 + 8]) = k1;
            *reinterpret_cast<bf16x8*>(&vbB[r * 72 + c0])     = v0;
            *reinterpret_cast<bf16x8*>(&vbB[r * 72 + c0 + 8]) = v1;
        }
        // ---- q row into registers ----
        {
            const bf16x8* qg = reinterpret_cast<const bf16x8*>(Qb + segbase + (size_t)r * 1024);
#pragma unroll
            for (int blk = 0; blk < 8; blk++) {
                bf16x8 qv = qg[blk];
#pragma unroll
                for (int j = 0; j < 8; j++) qf[blk * 8 + j] = (float)qv[j];
            }
        }
        __syncthreads();

        // ---- A_mem = (sigma(q) @ M) / (sigma(q)·z + eps) ----
        float am[16];
#pragma unroll
        for (int j = 0; j < 16; j++) am[j] = 0.f;
        float dq = 0.f;
#pragma unroll
        for (int k = 0; k < 64; k++) {
            float x = qf[k];
            float sg = x > 0.f ? x + 1.f : __expf(x);
            dq = __builtin_fmaf(sg, zsh[k], dq);
            const f32x4* Mr = reinterpret_cast<const f32x4*>(&Msh[k * 68 + c0]);
#pragma unroll
            for (int jj = 0; jj < 4; jj++) {
                f32x4 m4 = Mr[jj];
                am[jj * 4 + 0] = __builtin_fmaf(sg, m4[0], am[jj * 4 + 0]);
                am[jj * 4 + 1] = __builtin_fmaf(sg, m4[1], am[jj * 4 + 1]);
                am[jj * 4 + 2] = __builtin_fmaf(sg, m4[2], am[jj * 4 + 2]);
                am[jj * 4 + 3] = __builtin_fmaf(sg, m4[3], am[jj * 4 + 3]);
            }
        }
        float inv_dq = 1.f / (dq + 1e-6f);
#pragma unroll
        for (int j = 0; j < 16; j++) am[j] *= inv_dq;

        // ---- causal softmax scores; thread owns t = qd + 4*tt (interleaved for LDS banks) ----
        float p[16];
        float mx = -3.4e38f;
#pragma unroll
        for (int tt = 0; tt < 16; tt++) {
            int t = qd + (tt << 2);
            float sc = -3.4e38f;
            if (t <= r) {
                float a = 0.f;
                const bf16x8* kr = reinterpret_cast<const bf16x8*>(&kbB[t * 72]);
#pragma unroll
                for (int cb = 0; cb < 8; cb++) {
                    bf16x8 kv = kr[cb];
#pragma unroll
                    for (int j = 0; j < 8; j++) a = __builtin_fmaf(qf[cb * 8 + j], (float)kv[j], a);
                }
                sc = a * 0.125f;
            }
            p[tt] = sc;
            mx = fmaxf(mx, sc);
        }
        mx = fmaxf(mx, __shfl_xor(mx, 1));
        mx = fmaxf(mx, __shfl_xor(mx, 2));
        float sum = 0.f;
#pragma unroll
        for (int tt = 0; tt < 16; tt++) {
            int t = qd + (tt << 2);
            float e = (t <= r) ? __expf(p[tt] - mx) : 0.f;
            p[tt] = e;
            sum += e;
        }
        sum += __shfl_xor(sum, 1);
        sum += __shfl_xor(sum, 2);
        float inv_sum = 1.f / sum;
#pragma unroll
        for (int tt = 0; tt < 16; tt++) {
            int t = qd + (tt << 2);
            pT[t * 68 + r] = p[tt] * inv_sum;
        }
        __syncthreads();

        // ---- A_dot = P @ v ; combine and write A_s ----
        float ad[16];
#pragma unroll
        for (int j = 0; j < 16; j++) ad[j] = 0.f;
        for (int t = 0; t < 64; t++) {
            float pv = pT[t * 68 + r];
            const bf16x8* vr = reinterpret_cast<const bf16x8*>(&vbB[t * 72 + c0]);
            bf16x8 v0 = vr[0], v1 = vr[1];
#pragma unroll
            for (int j = 0; j < 8; j++) {
                ad[j]     = __builtin_fmaf(pv, (float)v0[j], ad[j]);
                ad[8 + j] = __builtin_fmaf(pv, (float)v1[j], ad[8 + j]);
            }
        }
        {
            bf16_t* op = outp + segbase + (size_t)r * 1024 + c0;
            bf16x8 o0, o1;
#pragma unroll
            for (int j = 0; j < 8; j++) {
                o0[j] = (bf16_t)(beta * am[j]     + omb * ad[j]);
                o1[j] = (bf16_t)(beta * am[8 + j] + omb * ad[8 + j]);
            }
            *reinterpret_cast<bf16x8*>(op)     = o0;
            *reinterpret_cast<bf16x8*>(op + 8) = o1;
        }
        __syncthreads();

        // ---- V_prev = (sigma(k) @ M) / (sigma(k)·z + eps); u = v - V_prev (in place) ----
        {
            float vp[16];
#pragma unroll
            for (int j = 0; j < 16; j++) vp[j] = 0.f;
            float dk_ = 0.f;
            for (int k = 0; k < 64; k++) {
                float x = (float)kbB[r * 72 + k];
                float sg = x > 0.f ? x + 1.f : __expf(x);
                dk_ = __builtin_fmaf(sg, zsh[k], dk_);
                const f32x4* Mr = reinterpret_cast<const f32x4*>(&Msh[k * 68 + c0]);
#pragma unroll
                for (int jj = 0; jj < 4; jj++) {
                    f32x4 m4 = Mr[jj];
                    vp[jj * 4 + 0] = __builtin_fmaf(sg, m4[0], vp[jj * 4 + 0]);
                    vp[jj * 4 + 1] = __builtin_fmaf(sg, m4[1], vp[jj * 4 + 1]);
                    vp[jj * 4 + 2] = __builtin_fmaf(sg, m4[2], vp[jj * 4 + 2]);
                    vp[jj * 4 + 3] = __builtin_fmaf(sg, m4[3], vp[jj * 4 + 3]);
                }
            }
            float inv_dk = 1.f / (dk_ + 1e-6f);
            bf16x8* vr = reinterpret_cast<bf16x8*>(&vbB[r * 72 + c0]);
            bf16x8 v0 = vr[0], v1 = vr[1];
            bf16x8 u0, u1;
#pragma unroll
            for (int j = 0; j < 8; j++) {
                u0[j] = (bf16_t)((float)v0[j] - vp[j] * inv_dk);
                u1[j] = (bf16_t)((float)v1[j] - vp[8 + j] * inv_dk);
            }
            vr[0] = u0;
            vr[1] = u1;
        }
        __syncthreads();

        // ---- M += sigma(k)^T @ u ; z += sum_t sigma(k) ----
        {
            float macc[16];
#pragma unroll
            for (int j = 0; j < 16; j++) macc[j] = 0.f;
            for (int t = 0; t < 64; t++) {
                float x = (float)kbB[t * 72 + r];
                float sg = x > 0.f ? x + 1.f : __expf(x);
                const bf16x8* ur = reinterpret_cast<const bf16x8*>(&vbB[t * 72 + c0]);
                bf16x8 u0 = ur[0], u1 = ur[1];
#pragma unroll
                for (int j = 0; j < 8; j++) {
                    macc[j]     = __builtin_fmaf(sg, (float)u0[j], macc[j]);
                    macc[8 + j] = __builtin_fmaf(sg, (float)u1[j], macc[8 + j]);
                }
            }
            float* Mr = &Msh[r * 68 + c0];
#pragma unroll
            for (int j = 0; j < 16; j++) Mr[j] += macc[j];
        }
        if (tid < 64) {
            int cz = tid;
            float za = 0.f;
            for (int t = 0; t < 64; t++) {
                float x = (float)kbB[t * 72 + cz];
                za += (x > 0.f ? x + 1.f : __expf(x));
            }
            zsh[cz] += za;
        }
        __syncthreads();
    }

    for (int i = tid; i < 4096; i += 256)
        Mfin[(size_t)bh * 4096 + i] = Msh[(i >> 6) * 68 + (i & 63)];
    if (tid < 64) zfin[bh * 64 + tid] = zsh[tid];
}

// ---------------- final means over batch ----------------
__global__ __launch_bounds__(256) void mean_kernel(const float* __restrict__ Mfin,
                                                   const float* __restrict__ zfin,
                                                   float* __restrict__ out) {
    int idx = blockIdx.x * 256 + threadIdx.x;
    if (idx < 65536) {
        out[16777216 + idx] = 0.25f * (Mfin[idx] + Mfin[idx + 65536] +
                                       Mfin[idx + 131072] + Mfin[idx + 196608]);
    } else if (idx < 66560) {
        int j = idx - 65536;
        out[16842752 + j] = 0.25f * (zfin[j] + zfin[j + 1024] + zfin[j + 2048] + zfin[j + 3072]);
    }
}

extern "C" void kernel_launch(void* const* d_in, const int* in_sizes, int n_in,
                              void* d_out, int out_size, void* d_ws, size_t ws_size,
                              hipStream_t stream) {
    const float* x      = (const float*)d_in[0];
    const float* Wq     = (const float*)d_in[1];
    const float* Wk     = (const float*)d_in[2];
    const float* Wv     = (const float*)d_in[3];
    const float* Wo     = (const float*)d_in[4];
    const float* beta_p = (const float*)d_in[5];
    float* out = (float*)d_out;
    char* ws = (char*)d_ws;

    const size_t NX = 16777216ull;  // B*T*D
    const size_t NW = 1048576ull;   // D*D

    bf16_t* xb  = (bf16_t*)ws;                          // 33,554,432 B
    bf16_t* Wqb = (bf16_t*)(ws + 33554432);             // 2 MB each
    bf16_t* Wkb = Wqb + NW;
    bf16_t* Wvb = Wkb + NW;
    bf16_t* Wob = Wvb + NW;
    bf16_t* Qb  = Wob + NW;                             // bf16 NX each
    bf16_t* Kb  = Qb + NX;
    bf16_t* Vb  = Kb + NX;
    bf16_t* Op  = Vb + NX;
    float*  Mfin = (float*)(Op + NX);                   // 4*16*4096 f32
    float*  zfin = Mfin + 262144;                       // 4*16*64 f32

    // casts
    cast_bf16_kernel<<<dim3(16384), dim3(256), 0, stream>>>(x, xb, (int)(NX / 4));
    cast_bf16_kernel<<<dim3(1024), dim3(256), 0, stream>>>(Wq, Wqb, (int)(NW / 4));
    cast_bf16_kernel<<<dim3(1024), dim3(256), 0, stream>>>(Wk, Wkb, (int)(NW / 4));
    cast_bf16_kernel<<<dim3(1024), dim3(256), 0, stream>>>(Wv, Wvb, (int)(NW / 4));
    cast_bf16_kernel<<<dim3(1024), dim3(256), 0, stream>>>(Wo, Wob, (int)(NW / 4));

    // projections: Q/K/V = x @ W^T  (bf16 out)
    gemm_bt<1><<<dim3(1024), dim3(256), 0, stream>>>(xb, Wqb, (void*)Qb, 16384, 1024, 1024);
    gemm_bt<1><<<dim3(1024), dim3(256), 0, stream>>>(xb, Wkb, (void*)Kb, 16384, 1024, 1024);
    gemm_bt<1><<<dim3(1024), dim3(256), 0, stream>>>(xb, Wvb, (void*)Vb, 16384, 1024, 1024);

    // sequential infini-attention scan
    infini_scan<<<dim3(64), dim3(256), 0, stream>>>(Qb, Kb, Vb, beta_p, Op, Mfin, zfin);

    // output projection (f32 out, straight into d_out)
    gemm_bt<0><<<dim3(1024), dim3(256), 0, stream>>>(Op, Wob, d_out, 16384, 1024, 1024);

    // batch means for M and z
    mean_kernel<<<dim3(260), dim3(256), 0, stream>>>(Mfin, zfin, out);
}

// Round 2
// 538.354 us; speedup vs baseline: 11.8402x; 11.8402x over previous
//
#include <hip/hip_runtime.h>

typedef __bf16 bf16_t;
typedef __bf16 bf16x8 __attribute__((ext_vector_type(8)));
typedef __bf16 bf16x4 __attribute__((ext_vector_type(4)));
typedef float  f32x4  __attribute__((ext_vector_type(4)));

// ---------------- f32 -> bf16 cast ----------------
__global__ __launch_bounds__(256) void cast_bf16_kernel(const float* __restrict__ in,
                                                        bf16_t* __restrict__ out, int n4) {
    int i = blockIdx.x * 256 + threadIdx.x;
    if (i >= n4) return;
    f32x4 v = *reinterpret_cast<const f32x4*>(in + (size_t)i * 4);
    bf16x4 o;
    o[0] = (bf16_t)v[0]; o[1] = (bf16_t)v[1]; o[2] = (bf16_t)v[2]; o[3] = (bf16_t)v[3];
    *reinterpret_cast<bf16x4*>(out + (size_t)i * 4) = o;
}

__device__ __forceinline__ bf16x8 sigma8(bf16x8 x) {
    bf16x8 o;
#pragma unroll
    for (int j = 0; j < 8; j++) {
        float f = (float)x[j];
        float sg = f > 0.f ? f + 1.f : __expf(f);
        o[j] = (bf16_t)sg;
    }
    return o;
}

// ---------------- C = A (MxK, row-major) * B^T (B is NxK row-major) ----------------
template <int OUT_BF16>
__global__ __launch_bounds__(256) void gemm_bt(const bf16_t* __restrict__ A,
                                               const bf16_t* __restrict__ Bm,
                                               void* __restrict__ Cv,
                                               int M, int N, int K) {
    __shared__ bf16_t As[128 * 32];
    __shared__ bf16_t Bs[128 * 32];
    const int nbn = N >> 7;
    const int nwg = (M >> 7) * nbn;
    int bid = blockIdx.x;
    int swz = ((nwg & 7) == 0) ? ((bid & 7) * (nwg >> 3) + (bid >> 3)) : bid;
    int bm = swz / nbn, bn = swz % nbn;

    int tid = threadIdx.x;
    int w = tid >> 6, lane = tid & 63;
    int wm = w >> 1, wn = w & 1;
    int lrow = lane & 15, lk = lane >> 4;

    int srow = tid >> 1;
    int scol = (tid & 1) << 4;
    const bf16_t* Ab = A  + (size_t)(bm * 128 + srow) * K + scol;
    const bf16_t* Bb = Bm + (size_t)(bn * 128 + srow) * K + scol;

    f32x4 acc[4][4];
#pragma unroll
    for (int i = 0; i < 4; i++)
#pragma unroll
        for (int j = 0; j < 4; j++) acc[i][j] = (f32x4){0.f, 0.f, 0.f, 0.f};

    for (int k0 = 0; k0 < K; k0 += 32) {
        bf16x8 a0 = *reinterpret_cast<const bf16x8*>(Ab + k0);
        bf16x8 a1 = *reinterpret_cast<const bf16x8*>(Ab + k0 + 8);
        bf16x8 b0 = *reinterpret_cast<const bf16x8*>(Bb + k0);
        bf16x8 b1 = *reinterpret_cast<const bf16x8*>(Bb + k0 + 8);
        __syncthreads();
        *reinterpret_cast<bf16x8*>(&As[srow * 32 + scol])     = a0;
        *reinterpret_cast<bf16x8*>(&As[srow * 32 + scol + 8]) = a1;
        *reinterpret_cast<bf16x8*>(&Bs[srow * 32 + scol])     = b0;
        *reinterpret_cast<bf16x8*>(&Bs[srow * 32 + scol + 8]) = b1;
        __syncthreads();
        bf16x8 af[4], bfr[4];
#pragma unroll
        for (int i = 0; i < 4; i++)
            af[i] = *reinterpret_cast<const bf16x8*>(&As[(wm * 64 + i * 16 + lrow) * 32 + lk * 8]);
#pragma unroll
        for (int i = 0; i < 4; i++)
            bfr[i] = *reinterpret_cast<const bf16x8*>(&Bs[(wn * 64 + i * 16 + lrow) * 32 + lk * 8]);
#pragma unroll
        for (int mi = 0; mi < 4; mi++)
#pragma unroll
            for (int ni = 0; ni < 4; ni++)
                acc[mi][ni] = __builtin_amdgcn_mfma_f32_16x16x32_bf16(af[mi], bfr[ni], acc[mi][ni], 0, 0, 0);
    }

    int row0 = bm * 128 + wm * 64 + lk * 4;
    int colb = bn * 128 + wn * 64 + lrow;
#pragma unroll
    for (int mi = 0; mi < 4; mi++)
#pragma unroll
        for (int ni = 0; ni < 4; ni++)
#pragma unroll
            for (int j = 0; j < 4; j++) {
                size_t idx = (size_t)(row0 + mi * 16 + j) * N + (colb + ni * 16);
                float v = acc[mi][ni][j];
                if (OUT_BF16) reinterpret_cast<bf16_t*>(Cv)[idx] = (bf16_t)v;
                else          reinterpret_cast<float*>(Cv)[idx]  = v;
            }
}

// ---------------- parallel local attention + sigma(k)^T + column sums ----------------
// grid: B*H*S = 4096 blocks, 256 threads (4 waves)
__global__ __launch_bounds__(256) void attn_kernel(const bf16_t* __restrict__ Qb,
                                                   const bf16_t* __restrict__ Kb,
                                                   const bf16_t* __restrict__ Vb,
                                                   bf16_t* __restrict__ skTg,
                                                   float* __restrict__ csum,
                                                   bf16_t* __restrict__ Adot) {
    __shared__ bf16_t kS[64 * 72];
    __shared__ bf16_t vS[64 * 72];
    __shared__ bf16_t skT[64 * 72];
    __shared__ bf16_t pS[64 * 72];
    __shared__ float  scr[64 * 68];

    int u = blockIdx.x;
    int bh = u >> 6, s = u & 63;
    int b = bh >> 4, h = bh & 15;
    int tid = threadIdx.x;
    int w = tid >> 6, lane = tid & 63;
    int lr = lane & 15, lk = lane >> 4;
    int r = tid >> 2, qd = tid & 3, c0 = qd << 4;

    size_t vseg = ((size_t)b * 4096 + s * 64) * 1024 + (size_t)h * 64;
    size_t sb = ((size_t)bh * 64 + s) * 4096;

    // stage k, v; sigma(k) transposed scatter
    {
        bf16x8 k0 = *reinterpret_cast<const bf16x8*>(Kb + vseg + (size_t)r * 1024 + c0);
        bf16x8 k1 = *reinterpret_cast<const bf16x8*>(Kb + vseg + (size_t)r * 1024 + c0 + 8);
        bf16x8 v0 = *reinterpret_cast<const bf16x8*>(Vb + vseg + (size_t)r * 1024 + c0);
        bf16x8 v1 = *reinterpret_cast<const bf16x8*>(Vb + vseg + (size_t)r * 1024 + c0 + 8);
        *reinterpret_cast<bf16x8*>(&kS[r * 72 + c0])     = k0;
        *reinterpret_cast<bf16x8*>(&kS[r * 72 + c0 + 8]) = k1;
        *reinterpret_cast<bf16x8*>(&vS[r * 72 + c0])     = v0;
        *reinterpret_cast<bf16x8*>(&vS[r * 72 + c0 + 8]) = v1;
        bf16x8 s0 = sigma8(k0), s1 = sigma8(k1);
#pragma unroll
        for (int j = 0; j < 8; j++) {
            skT[(c0 + j) * 72 + r]     = s0[j];
            skT[(c0 + 8 + j) * 72 + r] = s1[j];
        }
    }
    __syncthreads();

    // column sums of sigma(k); skT to global (coalesced)
    if (tid < 64) {
        float acc = 0.f;
#pragma unroll 8
        for (int t = 0; t < 64; t++) acc += (float)skT[tid * 72 + t];
        csum[((size_t)bh * 64 + s) * 64 + tid] = acc;
    }
    *reinterpret_cast<bf16x8*>(skTg + sb + (size_t)r * 64 + c0) =
        *reinterpret_cast<const bf16x8*>(&skT[r * 72 + c0]);
    *reinterpret_cast<bf16x8*>(skTg + sb + (size_t)r * 64 + c0 + 8) =
        *reinterpret_cast<const bf16x8*>(&skT[r * 72 + c0 + 8]);

    // scores = q @ k^T * 0.125 via MFMA; wave w owns rows 16w..16w+15
    {
        bf16x8 aq[2];
#pragma unroll
        for (int ks = 0; ks < 2; ks++)
            aq[ks] = *reinterpret_cast<const bf16x8*>(Qb + vseg + (size_t)(w * 16 + lr) * 1024 + lk * 8 + ks * 32);
        f32x4 sc[4];
#pragma unroll
        for (int ct = 0; ct < 4; ct++) {
            sc[ct] = (f32x4){0.f, 0.f, 0.f, 0.f};
#pragma unroll
            for (int ks = 0; ks < 2; ks++) {
                bf16x8 bfrag = *reinterpret_cast<const bf16x8*>(&kS[(ct * 16 + lr) * 72 + lk * 8 + ks * 32]);
                sc[ct] = __builtin_amdgcn_mfma_f32_16x16x32_bf16(aq[ks], bfrag, sc[ct], 0, 0, 0);
            }
        }
#pragma unroll
        for (int ct = 0; ct < 4; ct++)
#pragma unroll
            for (int j = 0; j < 4; j++)
                scr[(w * 16 + lk * 4 + j) * 68 + ct * 16 + lr] = sc[ct][j] * 0.125f;
    }
    __syncthreads();

    // causal softmax; thread (r, qd) owns cols c0..c0+15 of row r
    {
        float p[16];
        float mx = -3.4e38f;
        const float* srow_p = &scr[r * 68 + c0];
#pragma unroll
        for (int i = 0; i < 16; i++) {
            int c = c0 + i;
            float v = (c <= r) ? srow_p[i] : -3.4e38f;
            p[i] = v;
            mx = fmaxf(mx, v);
        }
        mx = fmaxf(mx, __shfl_xor(mx, 1));
        mx = fmaxf(mx, __shfl_xor(mx, 2));
        float sum = 0.f;
#pragma unroll
        for (int i = 0; i < 16; i++) {
            int c = c0 + i;
            float e = (c <= r) ? __expf(p[i] - mx) : 0.f;
            p[i] = e;
            sum += e;
        }
        sum += __shfl_xor(sum, 1);
        sum += __shfl_xor(sum, 2);
        float inv = 1.f / sum;
        bf16x8 p0, p1;
#pragma unroll
        for (int j = 0; j < 8; j++) {
            p0[j] = (bf16_t)(p[j] * inv);
            p1[j] = (bf16_t)(p[8 + j] * inv);
        }
        *reinterpret_cast<bf16x8*>(&pS[r * 72 + c0])     = p0;
        *reinterpret_cast<bf16x8*>(&pS[r * 72 + c0 + 8]) = p1;
    }
    __syncthreads();

    // A_dot = P @ v (VALU)
    {
        float ad[16];
#pragma unroll
        for (int j = 0; j < 16; j++) ad[j] = 0.f;
        for (int t = 0; t < 64; t++) {
            float pv = (float)pS[r * 72 + t];
            bf16x8 va = *reinterpret_cast<const bf16x8*>(&vS[t * 72 + c0]);
            bf16x8 vb = *reinterpret_cast<const bf16x8*>(&vS[t * 72 + c0 + 8]);
#pragma unroll
            for (int j = 0; j < 8; j++) {
                ad[j]     = __builtin_fmaf(pv, (float)va[j], ad[j]);
                ad[8 + j] = __builtin_fmaf(pv, (float)vb[j], ad[8 + j]);
            }
        }
        bf16x8 o0, o1;
#pragma unroll
        for (int j = 0; j < 8; j++) {
            o0[j] = (bf16_t)ad[j];
            o1[j] = (bf16_t)ad[8 + j];
        }
        *reinterpret_cast<bf16x8*>(Adot + sb + (size_t)r * 64 + c0)     = o0;
        *reinterpret_cast<bf16x8*>(Adot + sb + (size_t)r * 64 + c0 + 8) = o1;
    }
}

// ---------------- z prefix over segments ----------------
__global__ __launch_bounds__(64) void zprefix_kernel(const float* __restrict__ csum,
                                                     float* __restrict__ zx,
                                                     float* __restrict__ zfin) {
    int bh = blockIdx.x;
    int d = threadIdx.x;
    float z = 0.f;
    for (int s = 0; s < 64; s++) {
        size_t o = ((size_t)bh * 64 + s) * 64 + d;
        zx[o] = z;
        z += csum[o];
    }
    zfin[bh * 64 + d] = z;
}

// ---------------- denominators 1/(sigma . z + eps) ----------------
// grid 4096, 128 threads: tid<64 -> q row tid; tid>=64 -> k row tid-64
__global__ __launch_bounds__(128) void denom_kernel(const bf16_t* __restrict__ Qb,
                                                    const bf16_t* __restrict__ Kb,
                                                    const float* __restrict__ zx,
                                                    float* __restrict__ invq,
                                                    float* __restrict__ invk) {
    __shared__ float zL[64];
    int u = blockIdx.x;
    int bh = u >> 6, s = u & 63;
    int b = bh >> 4, h = bh & 15;
    int tid = threadIdx.x;
    if (tid < 64) zL[tid] = zx[((size_t)bh * 64 + s) * 64 + tid];
    __syncthreads();
    int row = tid & 63;
    const bf16_t* src = ((tid < 64) ? Qb : Kb) +
                        ((size_t)b * 4096 + s * 64 + row) * 1024 + (size_t)h * 64;
    float acc = 0.f;
#pragma unroll
    for (int blk = 0; blk < 8; blk++) {
        bf16x8 v = *reinterpret_cast<const bf16x8*>(src + blk * 8);
#pragma unroll
        for (int j = 0; j < 8; j++) {
            float f = (float)v[j];
            float sg = f > 0.f ? f + 1.f : __expf(f);
            sg = (float)(bf16_t)sg;   // match MFMA operand rounding
            acc = __builtin_fmaf(sg, zL[blk * 8 + j], acc);
        }
    }
    float inv = 1.f / (acc + 1e-6f);
    float* dst = (tid < 64) ? invq : invk;
    dst[((size_t)bh * 64 + s) * 64 + row] = inv;
}

// ---------------- MFMA-based sequential scan; M lives in MFMA accumulators ----------------
// grid 64 (one per b,h), 256 threads (4 waves)
__global__ __launch_bounds__(256) void scan_kernel(const bf16_t* __restrict__ Qb,
                                                   const bf16_t* __restrict__ Kb,
                                                   const bf16_t* __restrict__ Vb,
                                                   const bf16_t* __restrict__ skTg,
                                                   const bf16_t* __restrict__ Adot,
                                                   const float* __restrict__ invq,
                                                   const float* __restrict__ invk,
                                                   const float* __restrict__ beta_param,
                                                   bf16_t* __restrict__ Op,
                                                   float* __restrict__ Mfin) {
    __shared__ bf16_t MbfT[64 * 72];  // M^T, bf16 copy for MFMA B-operand
    __shared__ bf16_t uT[64 * 72];    // u^T = (v - V_prev)^T
    __shared__ bf16_t vS[64 * 72];
    __shared__ bf16_t adS[64 * 72];
    __shared__ bf16_t oS[64 * 72];    // combined output staging
    __shared__ float  invL[128];

    int bh = blockIdx.x;
    int b = bh >> 4, h = bh & 15;
    int tid = threadIdx.x;
    int w = tid >> 6, lane = tid & 63;
    int lr = lane & 15, lk = lane >> 4;
    int r = tid >> 2, qd = tid & 3, c0 = qd << 4;
    int rt0 = (w & 1) * 32;

    float beta = 1.f / (1.f + __expf(-beta_param[h]));
    float omb = 1.f - beta;

    for (int i = tid; i < 64 * 72; i += 256) MbfT[i] = (bf16_t)0.f;
    f32x4 Mreg[4];
#pragma unroll
    for (int ct = 0; ct < 4; ct++) Mreg[ct] = (f32x4){0.f, 0.f, 0.f, 0.f};

    size_t chbase = ((size_t)b * 4096) * 1024 + (size_t)h * 64;
    size_t sbase = (size_t)bh * 64 * 4096;
    __syncthreads();

    for (int s = 0; s < 64; s++) {
        size_t vseg = chbase + (size_t)s * 65536;
        size_t sb = sbase + (size_t)s * 4096;

        // ---- top staging: v, A_dot -> LDS; inv -> LDS; A-frags -> regs ----
        bf16x8 vv0 = *reinterpret_cast<const bf16x8*>(Vb + vseg + (size_t)r * 1024 + c0);
        bf16x8 vv1 = *reinterpret_cast<const bf16x8*>(Vb + vseg + (size_t)r * 1024 + c0 + 8);
        bf16x8 ad0 = *reinterpret_cast<const bf16x8*>(Adot + sb + (size_t)r * 64 + c0);
        bf16x8 ad1 = *reinterpret_cast<const bf16x8*>(Adot + sb + (size_t)r * 64 + c0 + 8);
        if (tid < 64)       invL[tid]      = invq[((size_t)bh * 64 + s) * 64 + tid];
        else if (tid < 128) invL[tid]      = invk[((size_t)bh * 64 + s) * 64 + (tid - 64)];

        const bf16_t* Xsrc = (w < 2) ? Qb : Kb;
        bf16x8 aX[2][2];
#pragma unroll
        for (int ti = 0; ti < 2; ti++)
#pragma unroll
            for (int ks = 0; ks < 2; ks++) {
                bf16x8 raw = *reinterpret_cast<const bf16x8*>(
                    Xsrc + vseg + (size_t)(rt0 + ti * 16 + lr) * 1024 + lk * 8 + ks * 32);
                aX[ti][ks] = sigma8(raw);
            }
        bf16x8 aT[2];
#pragma unroll
        for (int ks = 0; ks < 2; ks++)
            aT[ks] = *reinterpret_cast<const bf16x8*>(skTg + sb + (size_t)(w * 16 + lr) * 64 + lk * 8 + ks * 32);

        *reinterpret_cast<bf16x8*>(&vS[r * 72 + c0])      = vv0;
        *reinterpret_cast<bf16x8*>(&vS[r * 72 + c0 + 8])  = vv1;
        *reinterpret_cast<bf16x8*>(&adS[r * 72 + c0])     = ad0;
        *reinterpret_cast<bf16x8*>(&adS[r * 72 + c0 + 8]) = ad1;
        __syncthreads();   // A

        // ---- MFMA1: Y = [sigma(q); sigma(k)] @ M   (B = MbfT) ----
        f32x4 Y[2][4];
#pragma unroll
        for (int ti = 0; ti < 2; ti++)
#pragma unroll
            for (int ct = 0; ct < 4; ct++) {
                Y[ti][ct] = (f32x4){0.f, 0.f, 0.f, 0.f};
#pragma unroll
                for (int ks = 0; ks < 2; ks++) {
                    bf16x8 bfrag = *reinterpret_cast<const bf16x8*>(&MbfT[(ct * 16 + lr) * 72 + lk * 8 + ks * 32]);
                    Y[ti][ct] = __builtin_amdgcn_mfma_f32_16x16x32_bf16(aX[ti][ks], bfrag, Y[ti][ct], 0, 0, 0);
                }
            }

        // ---- epilogue ----
        if (w < 2) {
            // A_mem scaled; combine with A_dot -> oS
#pragma unroll
            for (int ti = 0; ti < 2; ti++)
#pragma unroll
                for (int ct = 0; ct < 4; ct++) {
                    int colc = ct * 16 + lr;
#pragma unroll
                    for (int j = 0; j < 4; j++) {
                        int rg = rt0 + ti * 16 + lk * 4 + j;
                        float am = Y[ti][ct][j] * invL[rg];
                        float o = beta * am + omb * (float)adS[rg * 72 + colc];
                        oS[rg * 72 + colc] = (bf16_t)o;
                    }
                }
        } else {
            // u = v - V_prev  -> uT (transposed, packed 4-row writes)
#pragma unroll
            for (int ti = 0; ti < 2; ti++)
#pragma unroll
                for (int ct = 0; ct < 4; ct++) {
                    int colc = ct * 16 + lr;
                    int rg0 = rt0 + ti * 16 + lk * 4;
                    bf16x4 pack;
#pragma unroll
                    for (int j = 0; j < 4; j++) {
                        float vp = Y[ti][ct][j] * invL[64 + rg0 + j];
                        pack[j] = (bf16_t)((float)vS[(rg0 + j) * 72 + colc] - vp);
                    }
                    *reinterpret_cast<bf16x4*>(&uT[colc * 72 + rg0]) = pack;
                }
        }
        __syncthreads();   // B

        // ---- cooperative store of combined output ----
        *reinterpret_cast<bf16x8*>(Op + vseg + (size_t)r * 1024 + c0) =
            *reinterpret_cast<const bf16x8*>(&oS[r * 72 + c0]);
        *reinterpret_cast<bf16x8*>(Op + vseg + (size_t)r * 1024 + c0 + 8) =
            *reinterpret_cast<const bf16x8*>(&oS[r * 72 + c0 + 8]);

        // ---- MFMA2: M += sigma(k)^T @ u  (accumulate straight into Mreg) ----
#pragma unroll
        for (int ct = 0; ct < 4; ct++) {
#pragma unroll
            for (int ks = 0; ks < 2; ks++) {
                bf16x8 bfrag = *reinterpret_cast<const bf16x8*>(&uT[(ct * 16 + lr) * 72 + lk * 8 + ks * 32]);
                Mreg[ct] = __builtin_amdgcn_mfma_f32_16x16x32_bf16(aT[ks], bfrag, Mreg[ct], 0, 0, 0);
            }
            // refresh bf16 M^T copy
            int colc = ct * 16 + lr;
            int i0 = w * 16 + lk * 4;
            bf16x4 mp;
#pragma unroll
            for (int j = 0; j < 4; j++) mp[j] = (bf16_t)Mreg[ct][j];
            *reinterpret_cast<bf16x4*>(&MbfT[colc * 72 + i0]) = mp;
        }
        __syncthreads();   // C
    }

    // write final M (f32) for the mean kernel
#pragma unroll
    for (int ct = 0; ct < 4; ct++)
#pragma unroll
        for (int j = 0; j < 4; j++) {
            int i = w * 16 + lk * 4 + j;
            int jc = ct * 16 + lr;
            Mfin[(size_t)bh * 4096 + (size_t)i * 64 + jc] = Mreg[ct][j];
        }
}

// ---------------- final means over batch ----------------
__global__ __launch_bounds__(256) void mean_kernel(const float* __restrict__ Mfin,
                                                   const float* __restrict__ zfin,
                                                   float* __restrict__ out) {
    int idx = blockIdx.x * 256 + threadIdx.x;
    if (idx < 65536) {
        out[16777216 + idx] = 0.25f * (Mfin[idx] + Mfin[idx + 65536] +
                                       Mfin[idx + 131072] + Mfin[idx + 196608]);
    } else if (idx < 66560) {
        int j = idx - 65536;
        out[16842752 + j] = 0.25f * (zfin[j] + zfin[j + 1024] + zfin[j + 2048] + zfin[j + 3072]);
    }
}

extern "C" void kernel_launch(void* const* d_in, const int* in_sizes, int n_in,
                              void* d_out, int out_size, void* d_ws, size_t ws_size,
                              hipStream_t stream) {
    const float* x      = (const float*)d_in[0];
    const float* Wq     = (const float*)d_in[1];
    const float* Wk     = (const float*)d_in[2];
    const float* Wv     = (const float*)d_in[3];
    const float* Wo     = (const float*)d_in[4];
    const float* beta_p = (const float*)d_in[5];
    float* out = (float*)d_out;
    char* ws = (char*)d_ws;

    const size_t NX = 16777216ull;  // B*T*D elements
    const size_t NW = 1048576ull;   // D*D elements

    // ws layout (bytes). Adot aliases xb (xb dead after QKV GEMMs; attn runs after).
    bf16_t* xb   = (bf16_t*)ws;                         // [0, 33.5MB)
    bf16_t* Adot = xb;                                  // alias
    bf16_t* Wqb  = (bf16_t*)(ws + 33554432);
    bf16_t* Wkb  = (bf16_t*)(ws + 35651584);
    bf16_t* Wvb  = (bf16_t*)(ws + 37748736);
    bf16_t* Wob  = (bf16_t*)(ws + 39845888);
    bf16_t* Qb   = (bf16_t*)(ws + 41943040);
    bf16_t* Kb   = (bf16_t*)(ws + 75497472);
    bf16_t* Vb   = (bf16_t*)(ws + 109051904);
    bf16_t* skT  = (bf16_t*)(ws + 142606336);
    bf16_t* Op   = (bf16_t*)(ws + 176160768);
    float*  csum = (float*)(ws + 209715200);            // 1MB
    float*  zx   = (float*)(ws + 210763776);            // 1MB
    float*  invq = (float*)(ws + 211812352);            // 1MB
    float*  invk = (float*)(ws + 212860928);            // 1MB
    float*  Mfin = (float*)(ws + 213909504);            // 1MB
    float*  zfin = (float*)(ws + 214958080);            // 16KB  (end ~215MB)

    cast_bf16_kernel<<<dim3(16384), dim3(256), 0, stream>>>(x, xb, (int)(NX / 4));
    cast_bf16_kernel<<<dim3(1024), dim3(256), 0, stream>>>(Wq, Wqb, (int)(NW / 4));
    cast_bf16_kernel<<<dim3(1024), dim3(256), 0, stream>>>(Wk, Wkb, (int)(NW / 4));
    cast_bf16_kernel<<<dim3(1024), dim3(256), 0, stream>>>(Wv, Wvb, (int)(NW / 4));
    cast_bf16_kernel<<<dim3(1024), dim3(256), 0, stream>>>(Wo, Wob, (int)(NW / 4));

    gemm_bt<1><<<dim3(1024), dim3(256), 0, stream>>>(xb, Wqb, (void*)Qb, 16384, 1024, 1024);
    gemm_bt<1><<<dim3(1024), dim3(256), 0, stream>>>(xb, Wkb, (void*)Kb, 16384, 1024, 1024);
    gemm_bt<1><<<dim3(1024), dim3(256), 0, stream>>>(xb, Wvb, (void*)Vb, 16384, 1024, 1024);

    attn_kernel<<<dim3(4096), dim3(256), 0, stream>>>(Qb, Kb, Vb, skT, csum, Adot);
    zprefix_kernel<<<dim3(64), dim3(64), 0, stream>>>(csum, zx, zfin);
    denom_kernel<<<dim3(4096), dim3(128), 0, stream>>>(Qb, Kb, zx, invq, invk);
    scan_kernel<<<dim3(64), dim3(256), 0, stream>>>(Qb, Kb, Vb, skT, Adot, invq, invk,
                                                    beta_p, Op, Mfin);

    gemm_bt<0><<<dim3(1024), dim3(256), 0, stream>>>(Op, Wob, d_out, 16384, 1024, 1024);
    mean_kernel<<<dim3(260), dim3(256), 0, stream>>>(Mfin, zfin, out);
}

// Round 3
// 449.606 us; speedup vs baseline: 14.1773x; 1.1974x over previous
//
#include <hip/hip_runtime.h>

typedef __bf16 bf16_t;
typedef __bf16 bf16x8 __attribute__((ext_vector_type(8)));
typedef __bf16 bf16x4 __attribute__((ext_vector_type(4)));
typedef float  f32x4  __attribute__((ext_vector_type(4)));

__device__ __forceinline__ void gload16(const bf16_t* g, bf16_t* l) {
    __builtin_amdgcn_global_load_lds(
        (const __attribute__((address_space(1))) void*)(g),
        (__attribute__((address_space(3))) void*)(l), 16, 0, 0);
}

// ---------------- f32 -> bf16 cast ----------------
__global__ __launch_bounds__(256) void cast_bf16_kernel(const float* __restrict__ in,
                                                        bf16_t* __restrict__ out, int n4) {
    int i = blockIdx.x * 256 + threadIdx.x;
    if (i >= n4) return;
    f32x4 v = *reinterpret_cast<const f32x4*>(in + (size_t)i * 4);
    bf16x4 o;
    o[0] = (bf16_t)v[0]; o[1] = (bf16_t)v[1]; o[2] = (bf16_t)v[2]; o[3] = (bf16_t)v[3];
    *reinterpret_cast<bf16x4*>(out + (size_t)i * 4) = o;
}

__device__ __forceinline__ bf16x8 sigma8(bf16x8 x) {
    bf16x8 o;
#pragma unroll
    for (int j = 0; j < 8; j++) {
        float f = (float)x[j];
        float sg = f > 0.f ? f + 1.f : __expf(f);
        o[j] = (bf16_t)sg;
    }
    return o;
}

// ---------------- C = A (MxK, row-major) * B^T (B is NxK row-major) ----------------
// m97 structure: 128x128 tile, BK=32, global_load_lds width=16 staging.
template <int OUT_BF16>
__global__ __launch_bounds__(256) void gemm_bt(const bf16_t* __restrict__ A,
                                               const bf16_t* __restrict__ Bm,
                                               void* __restrict__ Cv,
                                               int M, int N, int K) {
    __shared__ bf16_t As[128 * 32];
    __shared__ bf16_t Bs[128 * 32];
    const int nbn = N >> 7;
    const int nwg = (M >> 7) * nbn;
    int bid = blockIdx.x;
    int swz = ((nwg & 7) == 0) ? ((bid & 7) * (nwg >> 3) + (bid >> 3)) : bid;
    int bm = swz / nbn, bn = swz % nbn;

    int tid = threadIdx.x;
    int w = tid >> 6, lane = tid & 63;
    int wm = w >> 1, wn = w & 1;
    int lrow = lane & 15, lk = lane >> 4;

    // async staging addresses: wave w, call c fills rows c*64+w*16 .. +15
    int g_r = w * 16 + (lane >> 2);
    int g_c = (lane & 3) * 8;
    const bf16_t* Ag0 = A  + (size_t)(bm * 128 + g_r) * K + g_c;
    const bf16_t* Ag1 = Ag0 + (size_t)64 * K;
    const bf16_t* Bg0 = Bm + (size_t)(bn * 128 + g_r) * K + g_c;
    const bf16_t* Bg1 = Bg0 + (size_t)64 * K;
    bf16_t* Al0 = &As[(w * 16) * 32] + lane * 8;
    bf16_t* Al1 = &As[(64 + w * 16) * 32] + lane * 8;
    bf16_t* Bl0 = &Bs[(w * 16) * 32] + lane * 8;
    bf16_t* Bl1 = &Bs[(64 + w * 16) * 32] + lane * 8;

    f32x4 acc[4][4];
#pragma unroll
    for (int i = 0; i < 4; i++)
#pragma unroll
        for (int j = 0; j < 4; j++) acc[i][j] = (f32x4){0.f, 0.f, 0.f, 0.f};

    for (int k0 = 0; k0 < K; k0 += 32) {
        __syncthreads();  // previous iteration's LDS reads done
        gload16(Ag0 + k0, Al0);
        gload16(Ag1 + k0, Al1);
        gload16(Bg0 + k0, Bl0);
        gload16(Bg1 + k0, Bl1);
        __syncthreads();  // drains vmcnt -> tiles ready
        bf16x8 af[4], bfr[4];
#pragma unroll
        for (int i = 0; i < 4; i++)
            af[i] = *reinterpret_cast<const bf16x8*>(&As[(wm * 64 + i * 16 + lrow) * 32 + lk * 8]);
#pragma unroll
        for (int i = 0; i < 4; i++)
            bfr[i] = *reinterpret_cast<const bf16x8*>(&Bs[(wn * 64 + i * 16 + lrow) * 32 + lk * 8]);
#pragma unroll
        for (int mi = 0; mi < 4; mi++)
#pragma unroll
            for (int ni = 0; ni < 4; ni++)
                acc[mi][ni] = __builtin_amdgcn_mfma_f32_16x16x32_bf16(af[mi], bfr[ni], acc[mi][ni], 0, 0, 0);
    }

    int row0 = bm * 128 + wm * 64 + lk * 4;
    int colb = bn * 128 + wn * 64 + lrow;
#pragma unroll
    for (int mi = 0; mi < 4; mi++)
#pragma unroll
        for (int ni = 0; ni < 4; ni++)
#pragma unroll
            for (int j = 0; j < 4; j++) {
                size_t idx = (size_t)(row0 + mi * 16 + j) * N + (colb + ni * 16);
                float v = acc[mi][ni][j];
                if (OUT_BF16) reinterpret_cast<bf16_t*>(Cv)[idx] = (bf16_t)v;
                else          reinterpret_cast<float*>(Cv)[idx]  = v;
            }
}

// ---------------- parallel local attention + sigma(k)^T + column sums ----------------
// grid: B*H*S = 4096 blocks, 256 threads (4 waves)
__global__ __launch_bounds__(256) void attn_kernel(const bf16_t* __restrict__ Qb,
                                                   const bf16_t* __restrict__ Kb,
                                                   const bf16_t* __restrict__ Vb,
                                                   bf16_t* __restrict__ skTg,
                                                   float* __restrict__ csum,
                                                   bf16_t* __restrict__ Adot) {
    __shared__ bf16_t kS[64 * 72];
    __shared__ bf16_t vS[64 * 72];
    __shared__ bf16_t skT[64 * 72];
    __shared__ bf16_t vT[64 * 72];
    __shared__ bf16_t pS[64 * 72];
    __shared__ float  scr[64 * 68];

    int u = blockIdx.x;
    int bh = u >> 6, s = u & 63;
    int b = bh >> 4, h = bh & 15;
    int tid = threadIdx.x;
    int w = tid >> 6, lane = tid & 63;
    int lr = lane & 15, lk = lane >> 4;
    int r = tid >> 2, qd = tid & 3, c0 = qd << 4;

    size_t vseg = ((size_t)b * 4096 + s * 64) * 1024 + (size_t)h * 64;
    size_t sb = ((size_t)bh * 64 + s) * 4096;

    // stage k, v; sigma(k)^T and v^T scatters
    {
        bf16x8 k0 = *reinterpret_cast<const bf16x8*>(Kb + vseg + (size_t)r * 1024 + c0);
        bf16x8 k1 = *reinterpret_cast<const bf16x8*>(Kb + vseg + (size_t)r * 1024 + c0 + 8);
        bf16x8 v0 = *reinterpret_cast<const bf16x8*>(Vb + vseg + (size_t)r * 1024 + c0);
        bf16x8 v1 = *reinterpret_cast<const bf16x8*>(Vb + vseg + (size_t)r * 1024 + c0 + 8);
        *reinterpret_cast<bf16x8*>(&kS[r * 72 + c0])     = k0;
        *reinterpret_cast<bf16x8*>(&kS[r * 72 + c0 + 8]) = k1;
        *reinterpret_cast<bf16x8*>(&vS[r * 72 + c0])     = v0;
        *reinterpret_cast<bf16x8*>(&vS[r * 72 + c0 + 8]) = v1;
        bf16x8 s0 = sigma8(k0), s1 = sigma8(k1);
#pragma unroll
        for (int j = 0; j < 8; j++) {
            skT[(c0 + j) * 72 + r]     = s0[j];
            skT[(c0 + 8 + j) * 72 + r] = s1[j];
            vT[(c0 + j) * 72 + r]      = v0[j];
            vT[(c0 + 8 + j) * 72 + r]  = v1[j];
        }
    }
    __syncthreads();

    // column sums of sigma(k); skT to global (coalesced)
    if (tid < 64) {
        float acc = 0.f;
#pragma unroll 8
        for (int t = 0; t < 64; t++) acc += (float)skT[tid * 72 + t];
        csum[((size_t)bh * 64 + s) * 64 + tid] = acc;
    }
    *reinterpret_cast<bf16x8*>(skTg + sb + (size_t)r * 64 + c0) =
        *reinterpret_cast<const bf16x8*>(&skT[r * 72 + c0]);
    *reinterpret_cast<bf16x8*>(skTg + sb + (size_t)r * 64 + c0 + 8) =
        *reinterpret_cast<const bf16x8*>(&skT[r * 72 + c0 + 8]);

    // scores = q @ k^T * 0.125 via MFMA; wave w owns rows 16w..16w+15
    {
        bf16x8 aq[2];
#pragma unroll
        for (int ks = 0; ks < 2; ks++)
            aq[ks] = *reinterpret_cast<const bf16x8*>(Qb + vseg + (size_t)(w * 16 + lr) * 1024 + lk * 8 + ks * 32);
        f32x4 sc[4];
#pragma unroll
        for (int ct = 0; ct < 4; ct++) {
            sc[ct] = (f32x4){0.f, 0.f, 0.f, 0.f};
#pragma unroll
            for (int ks = 0; ks < 2; ks++) {
                bf16x8 bfrag = *reinterpret_cast<const bf16x8*>(&kS[(ct * 16 + lr) * 72 + lk * 8 + ks * 32]);
                sc[ct] = __builtin_amdgcn_mfma_f32_16x16x32_bf16(aq[ks], bfrag, sc[ct], 0, 0, 0);
            }
        }
#pragma unroll
        for (int ct = 0; ct < 4; ct++)
#pragma unroll
            for (int j = 0; j < 4; j++)
                scr[(w * 16 + lk * 4 + j) * 68 + ct * 16 + lr] = sc[ct][j] * 0.125f;
    }
    __syncthreads();

    // causal softmax; thread (r, qd) owns cols c0..c0+15 of row r
    {
        float p[16];
        float mx = -3.4e38f;
        const float* srow_p = &scr[r * 68 + c0];
#pragma unroll
        for (int i = 0; i < 16; i++) {
            int c = c0 + i;
            float v = (c <= r) ? srow_p[i] : -3.4e38f;
            p[i] = v;
            mx = fmaxf(mx, v);
        }
        mx = fmaxf(mx, __shfl_xor(mx, 1));
        mx = fmaxf(mx, __shfl_xor(mx, 2));
        float sum = 0.f;
#pragma unroll
        for (int i = 0; i < 16; i++) {
            int c = c0 + i;
            float e = (c <= r) ? __expf(p[i] - mx) : 0.f;
            p[i] = e;
            sum += e;
        }
        sum += __shfl_xor(sum, 1);
        sum += __shfl_xor(sum, 2);
        float inv = 1.f / sum;
        bf16x8 p0, p1;
#pragma unroll
        for (int j = 0; j < 8; j++) {
            p0[j] = (bf16_t)(p[j] * inv);
            p1[j] = (bf16_t)(p[8 + j] * inv);
        }
        *reinterpret_cast<bf16x8*>(&pS[r * 72 + c0])     = p0;
        *reinterpret_cast<bf16x8*>(&pS[r * 72 + c0 + 8]) = p1;
    }
    __syncthreads();

    // A_dot = P @ v via MFMA (b-operand = v^T rows); stage into kS (dead), then coalesced store
    {
        f32x4 ad[4];
#pragma unroll
        for (int ct = 0; ct < 4; ct++) {
            ad[ct] = (f32x4){0.f, 0.f, 0.f, 0.f};
#pragma unroll
            for (int ks = 0; ks < 2; ks++) {
                bf16x8 afrag = *reinterpret_cast<const bf16x8*>(&pS[(w * 16 + lr) * 72 + lk * 8 + ks * 32]);
                bf16x8 bfrag = *reinterpret_cast<const bf16x8*>(&vT[(ct * 16 + lr) * 72 + lk * 8 + ks * 32]);
                ad[ct] = __builtin_amdgcn_mfma_f32_16x16x32_bf16(afrag, bfrag, ad[ct], 0, 0, 0);
            }
        }
#pragma unroll
        for (int ct = 0; ct < 4; ct++)
#pragma unroll
            for (int j = 0; j < 4; j++)
                kS[(w * 16 + lk * 4 + j) * 72 + ct * 16 + lr] = (bf16_t)ad[ct][j];
    }
    __syncthreads();
    *reinterpret_cast<bf16x8*>(Adot + sb + (size_t)r * 64 + c0) =
        *reinterpret_cast<const bf16x8*>(&kS[r * 72 + c0]);
    *reinterpret_cast<bf16x8*>(Adot + sb + (size_t)r * 64 + c0 + 8) =
        *reinterpret_cast<const bf16x8*>(&kS[r * 72 + c0 + 8]);
}

// ---------------- z prefix over segments ----------------
__global__ __launch_bounds__(64) void zprefix_kernel(const float* __restrict__ csum,
                                                     float* __restrict__ zx,
                                                     float* __restrict__ zfin) {
    int bh = blockIdx.x;
    int d = threadIdx.x;
    float z = 0.f;
    for (int s = 0; s < 64; s++) {
        size_t o = ((size_t)bh * 64 + s) * 64 + d;
        zx[o] = z;
        z += csum[o];
    }
    zfin[bh * 64 + d] = z;
}

// ---------------- denominators 1/(sigma . z + eps) ----------------
__global__ __launch_bounds__(128) void denom_kernel(const bf16_t* __restrict__ Qb,
                                                    const bf16_t* __restrict__ Kb,
                                                    const float* __restrict__ zx,
                                                    float* __restrict__ invq,
                                                    float* __restrict__ invk) {
    __shared__ float zL[64];
    int u = blockIdx.x;
    int bh = u >> 6, s = u & 63;
    int b = bh >> 4, h = bh & 15;
    int tid = threadIdx.x;
    if (tid < 64) zL[tid] = zx[((size_t)bh * 64 + s) * 64 + tid];
    __syncthreads();
    int row = tid & 63;
    const bf16_t* src = ((tid < 64) ? Qb : Kb) +
                        ((size_t)b * 4096 + s * 64 + row) * 1024 + (size_t)h * 64;
    float acc = 0.f;
#pragma unroll
    for (int blk = 0; blk < 8; blk++) {
        bf16x8 v = *reinterpret_cast<const bf16x8*>(src + blk * 8);
#pragma unroll
        for (int j = 0; j < 8; j++) {
            float f = (float)v[j];
            float sg = f > 0.f ? f + 1.f : __expf(f);
            sg = (float)(bf16_t)sg;   // match MFMA operand rounding
            acc = __builtin_fmaf(sg, zL[blk * 8 + j], acc);
        }
    }
    float inv = 1.f / (acc + 1e-6f);
    float* dst = (tid < 64) ? invq : invk;
    dst[((size_t)bh * 64 + s) * 64 + row] = inv;
}

// ---------------- MFMA scan, software-pipelined (prefetch s+1), 2 barriers/step ----------------
// grid 64 (one per b,h), 256 threads (4 waves)
__global__ __launch_bounds__(256) void scan_kernel(const bf16_t* __restrict__ Qb,
                                                   const bf16_t* __restrict__ Kb,
                                                   const bf16_t* __restrict__ Vb,
                                                   const bf16_t* __restrict__ skTg,
                                                   const bf16_t* __restrict__ Adot,
                                                   const float* __restrict__ invq,
                                                   const float* __restrict__ invk,
                                                   const float* __restrict__ beta_param,
                                                   bf16_t* __restrict__ Op,
                                                   float* __restrict__ Mfin) {
    __shared__ bf16_t MbfT[64 * 72];  // M^T, bf16 copy (MFMA B-operand)
    __shared__ bf16_t uT[64 * 72];    // (v - V_prev)^T
    __shared__ bf16_t vS[64 * 72];
    __shared__ bf16_t adS[64 * 72];
    __shared__ bf16_t oS[64 * 72];
    __shared__ float  invL[128];

    int bh = blockIdx.x;
    int b = bh >> 4, h = bh & 15;
    int tid = threadIdx.x;
    int w = tid >> 6, lane = tid & 63;
    int lr = lane & 15, lk = lane >> 4;
    int r = tid >> 2, qd = tid & 3, c0 = qd << 4;
    int rt0 = (w & 1) * 32;

    float beta = 1.f / (1.f + __expf(-beta_param[h]));
    float omb = 1.f - beta;

    for (int i = tid; i < 64 * 72; i += 256) MbfT[i] = (bf16_t)0.f;
    f32x4 Mreg[4];
#pragma unroll
    for (int ct = 0; ct < 4; ct++) Mreg[ct] = (f32x4){0.f, 0.f, 0.f, 0.f};

    size_t chbase = ((size_t)b * 4096) * 1024 + (size_t)h * 64;
    size_t sbase = (size_t)bh * 64 * 4096;
    const bf16_t* Xsrc = (w < 2) ? Qb : Kb;

    // ---- prologue: load + stage segment 0 ----
    bf16x8 c_vv0 = *reinterpret_cast<const bf16x8*>(Vb + chbase + (size_t)r * 1024 + c0);
    bf16x8 c_vv1 = *reinterpret_cast<const bf16x8*>(Vb + chbase + (size_t)r * 1024 + c0 + 8);
    bf16x8 c_ad0 = *reinterpret_cast<const bf16x8*>(Adot + sbase + (size_t)r * 64 + c0);
    bf16x8 c_ad1 = *reinterpret_cast<const bf16x8*>(Adot + sbase + (size_t)r * 64 + c0 + 8);
    bf16x8 c_aX[2][2];
#pragma unroll
    for (int ti = 0; ti < 2; ti++)
#pragma unroll
        for (int ks = 0; ks < 2; ks++)
            c_aX[ti][ks] = sigma8(*reinterpret_cast<const bf16x8*>(
                Xsrc + chbase + (size_t)(rt0 + ti * 16 + lr) * 1024 + lk * 8 + ks * 32));
    bf16x8 c_aT0 = *reinterpret_cast<const bf16x8*>(skTg + sbase + (size_t)(w * 16 + lr) * 64 + lk * 8);
    bf16x8 c_aT1 = *reinterpret_cast<const bf16x8*>(skTg + sbase + (size_t)(w * 16 + lr) * 64 + lk * 8 + 32);
    float c_inv = 0.f;
    if (tid < 64)       c_inv = invq[(size_t)bh * 4096 + tid];
    else if (tid < 128) c_inv = invk[(size_t)bh * 4096 + (tid - 64)];

    *reinterpret_cast<bf16x8*>(&vS[r * 72 + c0])      = c_vv0;
    *reinterpret_cast<bf16x8*>(&vS[r * 72 + c0 + 8])  = c_vv1;
    *reinterpret_cast<bf16x8*>(&adS[r * 72 + c0])     = c_ad0;
    *reinterpret_cast<bf16x8*>(&adS[r * 72 + c0 + 8]) = c_ad1;
    if (tid < 128) invL[tid] = c_inv;
    __syncthreads();   // covers MbfT init + segment-0 staging

    for (int s = 0; s < 64; s++) {
        size_t vseg = chbase + (size_t)s * 65536;
        size_t sb = sbase + (size_t)s * 4096;

        // ===== phase 1 =====
        // prefetch s+1 into regs (hidden under MFMA1 + epilogue)
        bf16x8 n_vv0, n_vv1, n_ad0, n_ad1, n_raw[2][2], n_aT0, n_aT1;
        float n_inv = 0.f;
        if (s < 63) {
            size_t vs2 = vseg + 65536, sb2 = sb + 4096;
            n_vv0 = *reinterpret_cast<const bf16x8*>(Vb + vs2 + (size_t)r * 1024 + c0);
            n_vv1 = *reinterpret_cast<const bf16x8*>(Vb + vs2 + (size_t)r * 1024 + c0 + 8);
            n_ad0 = *reinterpret_cast<const bf16x8*>(Adot + sb2 + (size_t)r * 64 + c0);
            n_ad1 = *reinterpret_cast<const bf16x8*>(Adot + sb2 + (size_t)r * 64 + c0 + 8);
#pragma unroll
            for (int ti = 0; ti < 2; ti++)
#pragma unroll
                for (int ks = 0; ks < 2; ks++)
                    n_raw[ti][ks] = *reinterpret_cast<const bf16x8*>(
                        Xsrc + vs2 + (size_t)(rt0 + ti * 16 + lr) * 1024 + lk * 8 + ks * 32);
            n_aT0 = *reinterpret_cast<const bf16x8*>(skTg + sb2 + (size_t)(w * 16 + lr) * 64 + lk * 8);
            n_aT1 = *reinterpret_cast<const bf16x8*>(skTg + sb2 + (size_t)(w * 16 + lr) * 64 + lk * 8 + 32);
            if (tid < 64)       n_inv = invq[(size_t)bh * 4096 + (size_t)(s + 1) * 64 + tid];
            else if (tid < 128) n_inv = invk[(size_t)bh * 4096 + (size_t)(s + 1) * 64 + (tid - 64)];
        }

        // MFMA1: Y = [sigma(q); sigma(k)] @ M
        f32x4 Y[2][4];
#pragma unroll
        for (int ti = 0; ti < 2; ti++)
#pragma unroll
            for (int ct = 0; ct < 4; ct++) {
                Y[ti][ct] = (f32x4){0.f, 0.f, 0.f, 0.f};
#pragma unroll
                for (int ks = 0; ks < 2; ks++) {
                    bf16x8 bfrag = *reinterpret_cast<const bf16x8*>(&MbfT[(ct * 16 + lr) * 72 + lk * 8 + ks * 32]);
                    Y[ti][ct] = __builtin_amdgcn_mfma_f32_16x16x32_bf16(c_aX[ti][ks], bfrag, Y[ti][ct], 0, 0, 0);
                }
            }

        // epilogue
        if (w < 2) {
#pragma unroll
            for (int ti = 0; ti < 2; ti++)
#pragma unroll
                for (int ct = 0; ct < 4; ct++) {
                    int colc = ct * 16 + lr;
#pragma unroll
                    for (int j = 0; j < 4; j++) {
                        int rg = rt0 + ti * 16 + lk * 4 + j;
                        float am = Y[ti][ct][j] * invL[rg];
                        float o = beta * am + omb * (float)adS[rg * 72 + colc];
                        oS[rg * 72 + colc] = (bf16_t)o;
                    }
                }
        } else {
#pragma unroll
            for (int ti = 0; ti < 2; ti++)
#pragma unroll
                for (int ct = 0; ct < 4; ct++) {
                    int colc = ct * 16 + lr;
                    int rg0 = rt0 + ti * 16 + lk * 4;
                    bf16x4 pack;
#pragma unroll
                    for (int j = 0; j < 4; j++) {
                        float vp = Y[ti][ct][j] * invL[64 + rg0 + j];
                        pack[j] = (bf16_t)((float)vS[(rg0 + j) * 72 + colc] - vp);
                    }
                    *reinterpret_cast<bf16x4*>(&uT[colc * 72 + rg0]) = pack;
                }
        }
        __syncthreads();   // B

        // ===== phase 2 =====
        // combined output store
        *reinterpret_cast<bf16x8*>(Op + vseg + (size_t)r * 1024 + c0) =
            *reinterpret_cast<const bf16x8*>(&oS[r * 72 + c0]);
        *reinterpret_cast<bf16x8*>(Op + vseg + (size_t)r * 1024 + c0 + 8) =
            *reinterpret_cast<const bf16x8*>(&oS[r * 72 + c0 + 8]);

        // MFMA2: M += sigma(k)^T @ u ; refresh bf16 M^T
#pragma unroll
        for (int ct = 0; ct < 4; ct++) {
            {
                bf16x8 bfrag = *reinterpret_cast<const bf16x8*>(&uT[(ct * 16 + lr) * 72 + lk * 8]);
                Mreg[ct] = __builtin_amdgcn_mfma_f32_16x16x32_bf16(c_aT0, bfrag, Mreg[ct], 0, 0, 0);
            }
            {
                bf16x8 bfrag = *reinterpret_cast<const bf16x8*>(&uT[(ct * 16 + lr) * 72 + lk * 8 + 32]);
                Mreg[ct] = __builtin_amdgcn_mfma_f32_16x16x32_bf16(c_aT1, bfrag, Mreg[ct], 0, 0, 0);
            }
            int colc = ct * 16 + lr;
            int i0 = w * 16 + lk * 4;
            bf16x4 mp;
#pragma unroll
            for (int j = 0; j < 4; j++) mp[j] = (bf16_t)Mreg[ct][j];
            *reinterpret_cast<bf16x4*>(&MbfT[colc * 72 + i0]) = mp;
        }

        // rotate prefetched regs -> current; stage s+1 into LDS
        if (s < 63) {
#pragma unroll
            for (int ti = 0; ti < 2; ti++)
#pragma unroll
                for (int ks = 0; ks < 2; ks++)
                    c_aX[ti][ks] = sigma8(n_raw[ti][ks]);
            c_aT0 = n_aT0; c_aT1 = n_aT1;
            *reinterpret_cast<bf16x8*>(&vS[r * 72 + c0])      = n_vv0;
            *reinterpret_cast<bf16x8*>(&vS[r * 72 + c0 + 8])  = n_vv1;
            *reinterpret_cast<bf16x8*>(&adS[r * 72 + c0])     = n_ad0;
            *reinterpret_cast<bf16x8*>(&adS[r * 72 + c0 + 8]) = n_ad1;
            if (tid < 128) invL[tid] = n_inv;
        }
        __syncthreads();   // C: MbfT + next staging ready
    }

    // final M (f32) for the mean kernel
#pragma unroll
    for (int ct = 0; ct < 4; ct++)
#pragma unroll
        for (int j = 0; j < 4; j++) {
            int i = w * 16 + lk * 4 + j;
            int jc = ct * 16 + lr;
            Mfin[(size_t)bh * 4096 + (size_t)i * 64 + jc] = Mreg[ct][j];
        }
}

// ---------------- final means over batch ----------------
__global__ __launch_bounds__(256) void mean_kernel(const float* __restrict__ Mfin,
                                                   const float* __restrict__ zfin,
                                                   float* __restrict__ out) {
    int idx = blockIdx.x * 256 + threadIdx.x;
    if (idx < 65536) {
        out[16777216 + idx] = 0.25f * (Mfin[idx] + Mfin[idx + 65536] +
                                       Mfin[idx + 131072] + Mfin[idx + 196608]);
    } else if (idx < 66560) {
        int j = idx - 65536;
        out[16842752 + j] = 0.25f * (zfin[j] + zfin[j + 1024] + zfin[j + 2048] + zfin[j + 3072]);
    }
}

extern "C" void kernel_launch(void* const* d_in, const int* in_sizes, int n_in,
                              void* d_out, int out_size, void* d_ws, size_t ws_size,
                              hipStream_t stream) {
    const float* x      = (const float*)d_in[0];
    const float* Wq     = (const float*)d_in[1];
    const float* Wk     = (const float*)d_in[2];
    const float* Wv     = (const float*)d_in[3];
    const float* Wo     = (const float*)d_in[4];
    const float* beta_p = (const float*)d_in[5];
    float* out = (float*)d_out;
    char* ws = (char*)d_ws;

    const size_t NX = 16777216ull;  // B*T*D elements
    const size_t NW = 1048576ull;   // D*D elements

    bf16_t* xb   = (bf16_t*)ws;
    bf16_t* Adot = xb;                                  // alias (xb dead after QKV GEMMs)
    bf16_t* Wqb  = (bf16_t*)(ws + 33554432);
    bf16_t* Wkb  = (bf16_t*)(ws + 35651584);
    bf16_t* Wvb  = (bf16_t*)(ws + 37748736);
    bf16_t* Wob  = (bf16_t*)(ws + 39845888);
    bf16_t* Qb   = (bf16_t*)(ws + 41943040);
    bf16_t* Kb   = (bf16_t*)(ws + 75497472);
    bf16_t* Vb   = (bf16_t*)(ws + 109051904);
    bf16_t* skT  = (bf16_t*)(ws + 142606336);
    bf16_t* Op   = (bf16_t*)(ws + 176160768);
    float*  csum = (float*)(ws + 209715200);
    float*  zx   = (float*)(ws + 210763776);
    float*  invq = (float*)(ws + 211812352);
    float*  invk = (float*)(ws + 212860928);
    float*  Mfin = (float*)(ws + 213909504);
    float*  zfin = (float*)(ws + 214958080);

    cast_bf16_kernel<<<dim3(16384), dim3(256), 0, stream>>>(x, xb, (int)(NX / 4));
    cast_bf16_kernel<<<dim3(1024), dim3(256), 0, stream>>>(Wq, Wqb, (int)(NW / 4));
    cast_bf16_kernel<<<dim3(1024), dim3(256), 0, stream>>>(Wk, Wkb, (int)(NW / 4));
    cast_bf16_kernel<<<dim3(1024), dim3(256), 0, stream>>>(Wv, Wvb, (int)(NW / 4));
    cast_bf16_kernel<<<dim3(1024), dim3(256), 0, stream>>>(Wo, Wob, (int)(NW / 4));

    gemm_bt<1><<<dim3(1024), dim3(256), 0, stream>>>(xb, Wqb, (void*)Qb, 16384, 1024, 1024);
    gemm_bt<1><<<dim3(1024), dim3(256), 0, stream>>>(xb, Wkb, (void*)Kb, 16384, 1024, 1024);
    gemm_bt<1><<<dim3(1024), dim3(256), 0, stream>>>(xb, Wvb, (void*)Vb, 16384, 1024, 1024);

    attn_kernel<<<dim3(4096), dim3(256), 0, stream>>>(Qb, Kb, Vb, skT, csum, Adot);
    zprefix_kernel<<<dim3(64), dim3(64), 0, stream>>>(csum, zx, zfin);
    denom_kernel<<<dim3(4096), dim3(128), 0, stream>>>(Qb, Kb, zx, invq, invk);
    scan_kernel<<<dim3(64), dim3(256), 0, stream>>>(Qb, Kb, Vb, skT, Adot, invq, invk,
                                                    beta_p, Op, Mfin);

    gemm_bt<0><<<dim3(1024), dim3(256), 0, stream>>>(Op, Wob, d_out, 16384, 1024, 1024);
    mean_kernel<<<dim3(260), dim3(256), 0, stream>>>(Mfin, zfin, out);
}

// Round 5
// 413.283 us; speedup vs baseline: 15.4234x; 1.0879x over previous
//
#include <hip/hip_runtime.h>

typedef __bf16 bf16_t;
typedef __bf16 bf16x8 __attribute__((ext_vector_type(8)));
typedef __bf16 bf16x4 __attribute__((ext_vector_type(4)));
typedef float  f32x4  __attribute__((ext_vector_type(4)));

__device__ __forceinline__ void gload16(const bf16_t* g, bf16_t* l) {
    __builtin_amdgcn_global_load_lds(
        (const __attribute__((address_space(1))) void*)(g),
        (__attribute__((address_space(3))) void*)(l), 16, 0, 0);
}

// ---------------- f32 -> bf16 cast ----------------
__global__ __launch_bounds__(256) void cast_bf16_kernel(const float* __restrict__ in,
                                                        bf16_t* __restrict__ out, int n4) {
    int i = blockIdx.x * 256 + threadIdx.x;
    if (i >= n4) return;
    f32x4 v = *reinterpret_cast<const f32x4*>(in + (size_t)i * 4);
    bf16x4 o;
    o[0] = (bf16_t)v[0]; o[1] = (bf16_t)v[1]; o[2] = (bf16_t)v[2]; o[3] = (bf16_t)v[3];
    *reinterpret_cast<bf16x4*>(out + (size_t)i * 4) = o;
}

__device__ __forceinline__ bf16x8 sigma8(bf16x8 x) {
    bf16x8 o;
#pragma unroll
    for (int j = 0; j < 8; j++) {
        float f = (float)x[j];
        float sg = f > 0.f ? f + 1.f : __expf(f);
        o[j] = (bf16_t)sg;
    }
    return o;
}

// ---------------- C = A (MxK, row-major) * B^T (B is NxK row-major) ----------------
template <int OUT_BF16>
__global__ __launch_bounds__(256) void gemm_bt(const bf16_t* __restrict__ A,
                                               const bf16_t* __restrict__ Bm,
                                               void* __restrict__ Cv,
                                               int M, int N, int K) {
    __shared__ bf16_t As[128 * 32];
    __shared__ bf16_t Bs[128 * 32];
    const int nbn = N >> 7;
    const int nwg = (M >> 7) * nbn;
    int bid = blockIdx.x;
    int swz = ((nwg & 7) == 0) ? ((bid & 7) * (nwg >> 3) + (bid >> 3)) : bid;
    int bm = swz / nbn, bn = swz % nbn;

    int tid = threadIdx.x;
    int w = tid >> 6, lane = tid & 63;
    int wm = w >> 1, wn = w & 1;
    int lrow = lane & 15, lk = lane >> 4;

    int g_r = w * 16 + (lane >> 2);
    int g_c = (lane & 3) * 8;
    const bf16_t* Ag0 = A  + (size_t)(bm * 128 + g_r) * K + g_c;
    const bf16_t* Ag1 = Ag0 + (size_t)64 * K;
    const bf16_t* Bg0 = Bm + (size_t)(bn * 128 + g_r) * K + g_c;
    const bf16_t* Bg1 = Bg0 + (size_t)64 * K;
    bf16_t* Al0 = &As[(w * 16) * 32] + lane * 8;
    bf16_t* Al1 = &As[(64 + w * 16) * 32] + lane * 8;
    bf16_t* Bl0 = &Bs[(w * 16) * 32] + lane * 8;
    bf16_t* Bl1 = &Bs[(64 + w * 16) * 32] + lane * 8;

    f32x4 acc[4][4];
#pragma unroll
    for (int i = 0; i < 4; i++)
#pragma unroll
        for (int j = 0; j < 4; j++) acc[i][j] = (f32x4){0.f, 0.f, 0.f, 0.f};

    for (int k0 = 0; k0 < K; k0 += 32) {
        __syncthreads();
        gload16(Ag0 + k0, Al0);
        gload16(Ag1 + k0, Al1);
        gload16(Bg0 + k0, Bl0);
        gload16(Bg1 + k0, Bl1);
        __syncthreads();
        bf16x8 af[4], bfr[4];
#pragma unroll
        for (int i = 0; i < 4; i++)
            af[i] = *reinterpret_cast<const bf16x8*>(&As[(wm * 64 + i * 16 + lrow) * 32 + lk * 8]);
#pragma unroll
        for (int i = 0; i < 4; i++)
            bfr[i] = *reinterpret_cast<const bf16x8*>(&Bs[(wn * 64 + i * 16 + lrow) * 32 + lk * 8]);
#pragma unroll
        for (int mi = 0; mi < 4; mi++)
#pragma unroll
            for (int ni = 0; ni < 4; ni++)
                acc[mi][ni] = __builtin_amdgcn_mfma_f32_16x16x32_bf16(af[mi], bfr[ni], acc[mi][ni], 0, 0, 0);
    }

    int row0 = bm * 128 + wm * 64 + lk * 4;
    int colb = bn * 128 + wn * 64 + lrow;
#pragma unroll
    for (int mi = 0; mi < 4; mi++)
#pragma unroll
        for (int ni = 0; ni < 4; ni++)
#pragma unroll
            for (int j = 0; j < 4; j++) {
                size_t idx = (size_t)(row0 + mi * 16 + j) * N + (colb + ni * 16);
                float v = acc[mi][ni][j];
                if (OUT_BF16) reinterpret_cast<bf16_t*>(Cv)[idx] = (bf16_t)v;
                else          reinterpret_cast<float*>(Cv)[idx]  = v;
            }
}

// ---------------- parallel local attention; writes sigma(k) in place over Kb,
// v^T in place over Vb, sigma(k)^T dense, column sums, A_dot ----------------
__global__ __launch_bounds__(256) void attn_kernel(const bf16_t* __restrict__ Qb,
                                                   bf16_t* __restrict__ Kb,
                                                   bf16_t* __restrict__ Vb,
                                                   bf16_t* __restrict__ skTg,
                                                   float* __restrict__ csum,
                                                   bf16_t* __restrict__ Adot) {
    __shared__ bf16_t kS[64 * 72];
    __shared__ bf16_t vS[64 * 72];
    __shared__ bf16_t skT[64 * 72];
    __shared__ bf16_t vT[64 * 72];
    __shared__ bf16_t pS[64 * 72];
    __shared__ float  scr[64 * 68];

    int u = blockIdx.x;
    int bh = u >> 6, s = u & 63;
    int b = bh >> 4, h = bh & 15;
    int tid = threadIdx.x;
    int w = tid >> 6, lane = tid & 63;
    int lr = lane & 15, lk = lane >> 4;
    int r = tid >> 2, qd = tid & 3, c0 = qd << 4;

    size_t vseg = ((size_t)b * 4096 + s * 64) * 1024 + (size_t)h * 64;
    size_t sb = ((size_t)bh * 64 + s) * 4096;

    // stage k, v; sigma(k)^T and v^T scatters; sigma(k) in-place store
    {
        bf16x8 k0 = *reinterpret_cast<const bf16x8*>(Kb + vseg + (size_t)r * 1024 + c0);
        bf16x8 k1 = *reinterpret_cast<const bf16x8*>(Kb + vseg + (size_t)r * 1024 + c0 + 8);
        bf16x8 v0 = *reinterpret_cast<const bf16x8*>(Vb + vseg + (size_t)r * 1024 + c0);
        bf16x8 v1 = *reinterpret_cast<const bf16x8*>(Vb + vseg + (size_t)r * 1024 + c0 + 8);
        *reinterpret_cast<bf16x8*>(&kS[r * 72 + c0])     = k0;
        *reinterpret_cast<bf16x8*>(&kS[r * 72 + c0 + 8]) = k1;
        *reinterpret_cast<bf16x8*>(&vS[r * 72 + c0])     = v0;
        *reinterpret_cast<bf16x8*>(&vS[r * 72 + c0 + 8]) = v1;
        bf16x8 s0 = sigma8(k0), s1 = sigma8(k1);
        *reinterpret_cast<bf16x8*>(Kb + vseg + (size_t)r * 1024 + c0)     = s0;
        *reinterpret_cast<bf16x8*>(Kb + vseg + (size_t)r * 1024 + c0 + 8) = s1;
#pragma unroll
        for (int j = 0; j < 8; j++) {
            skT[(c0 + j) * 72 + r]     = s0[j];
            skT[(c0 + 8 + j) * 72 + r] = s1[j];
            vT[(c0 + j) * 72 + r]      = v0[j];
            vT[(c0 + 8 + j) * 72 + r]  = v1[j];
        }
    }
    __syncthreads();

    // column sums of sigma(k); skT + v^T to global (coalesced)
    if (tid < 64) {
        float acc = 0.f;
#pragma unroll 8
        for (int t = 0; t < 64; t++) acc += (float)skT[tid * 72 + t];
        csum[((size_t)bh * 64 + s) * 64 + tid] = acc;
    }
    *reinterpret_cast<bf16x8*>(skTg + sb + (size_t)r * 64 + c0) =
        *reinterpret_cast<const bf16x8*>(&skT[r * 72 + c0]);
    *reinterpret_cast<bf16x8*>(skTg + sb + (size_t)r * 64 + c0 + 8) =
        *reinterpret_cast<const bf16x8*>(&skT[r * 72 + c0 + 8]);
    *reinterpret_cast<bf16x8*>(Vb + vseg + (size_t)r * 1024 + c0) =
        *reinterpret_cast<const bf16x8*>(&vT[r * 72 + c0]);
    *reinterpret_cast<bf16x8*>(Vb + vseg + (size_t)r * 1024 + c0 + 8) =
        *reinterpret_cast<const bf16x8*>(&vT[r * 72 + c0 + 8]);

    // scores = q @ k^T * 0.125 via MFMA
    {
        bf16x8 aq[2];
#pragma unroll
        for (int ks = 0; ks < 2; ks++)
            aq[ks] = *reinterpret_cast<const bf16x8*>(Qb + vseg + (size_t)(w * 16 + lr) * 1024 + lk * 8 + ks * 32);
        f32x4 sc[4];
#pragma unroll
        for (int ct = 0; ct < 4; ct++) {
            sc[ct] = (f32x4){0.f, 0.f, 0.f, 0.f};
#pragma unroll
            for (int ks = 0; ks < 2; ks++) {
                bf16x8 bfrag = *reinterpret_cast<const bf16x8*>(&kS[(ct * 16 + lr) * 72 + lk * 8 + ks * 32]);
                sc[ct] = __builtin_amdgcn_mfma_f32_16x16x32_bf16(aq[ks], bfrag, sc[ct], 0, 0, 0);
            }
        }
#pragma unroll
        for (int ct = 0; ct < 4; ct++)
#pragma unroll
            for (int j = 0; j < 4; j++)
                scr[(w * 16 + lk * 4 + j) * 68 + ct * 16 + lr] = sc[ct][j] * 0.125f;
    }
    __syncthreads();

    // causal softmax; thread (r, qd) owns cols c0..c0+15 of row r
    {
        float p[16];
        float mx = -3.4e38f;
        const float* srow_p = &scr[r * 68 + c0];
#pragma unroll
        for (int i = 0; i < 16; i++) {
            int c = c0 + i;
            float v = (c <= r) ? srow_p[i] : -3.4e38f;
            p[i] = v;
            mx = fmaxf(mx, v);
        }
        mx = fmaxf(mx, __shfl_xor(mx, 1));
        mx = fmaxf(mx, __shfl_xor(mx, 2));
        float sum = 0.f;
#pragma unroll
        for (int i = 0; i < 16; i++) {
            int c = c0 + i;
            float e = (c <= r) ? __expf(p[i] - mx) : 0.f;
            p[i] = e;
            sum += e;
        }
        sum += __shfl_xor(sum, 1);
        sum += __shfl_xor(sum, 2);
        float inv = 1.f / sum;
        bf16x8 p0, p1;
#pragma unroll
        for (int j = 0; j < 8; j++) {
            p0[j] = (bf16_t)(p[j] * inv);
            p1[j] = (bf16_t)(p[8 + j] * inv);
        }
        *reinterpret_cast<bf16x8*>(&pS[r * 72 + c0])     = p0;
        *reinterpret_cast<bf16x8*>(&pS[r * 72 + c0 + 8]) = p1;
    }
    __syncthreads();

    // A_dot = P @ v via MFMA (B = v^T rows); stage into kS (dead), coalesced store
    {
        f32x4 ad[4];
#pragma unroll
        for (int ct = 0; ct < 4; ct++) {
            ad[ct] = (f32x4){0.f, 0.f, 0.f, 0.f};
#pragma unroll
            for (int ks = 0; ks < 2; ks++) {
                bf16x8 afrag = *reinterpret_cast<const bf16x8*>(&pS[(w * 16 + lr) * 72 + lk * 8 + ks * 32]);
                bf16x8 bfrag = *reinterpret_cast<const bf16x8*>(&vT[(ct * 16 + lr) * 72 + lk * 8 + ks * 32]);
                ad[ct] = __builtin_amdgcn_mfma_f32_16x16x32_bf16(afrag, bfrag, ad[ct], 0, 0, 0);
            }
        }
#pragma unroll
        for (int ct = 0; ct < 4; ct++)
#pragma unroll
            for (int j = 0; j < 4; j++)
                kS[(w * 16 + lk * 4 + j) * 72 + ct * 16 + lr] = (bf16_t)ad[ct][j];
    }
    __syncthreads();
    *reinterpret_cast<bf16x8*>(Adot + sb + (size_t)r * 64 + c0) =
        *reinterpret_cast<const bf16x8*>(&kS[r * 72 + c0]);
    *reinterpret_cast<bf16x8*>(Adot + sb + (size_t)r * 64 + c0 + 8) =
        *reinterpret_cast<const bf16x8*>(&kS[r * 72 + c0 + 8]);
}

// ---------------- z prefix over segments ----------------
__global__ __launch_bounds__(64) void zprefix_kernel(const float* __restrict__ csum,
                                                     float* __restrict__ zx,
                                                     float* __restrict__ zfin) {
    int bh = blockIdx.x;
    int d = threadIdx.x;
    float z = 0.f;
    for (int s = 0; s < 64; s++) {
        size_t o = ((size_t)bh * 64 + s) * 64 + d;
        zx[o] = z;
        z += csum[o];
    }
    zfin[bh * 64 + d] = z;
}

// ---------------- denominators 1/(sigma . z + eps) ----------------
__global__ __launch_bounds__(128) void denom_kernel(const bf16_t* __restrict__ Qb,
                                                    const bf16_t* __restrict__ sK,
                                                    const float* __restrict__ zx,
                                                    float* __restrict__ invq,
                                                    float* __restrict__ invk) {
    __shared__ float zL[64];
    int u = blockIdx.x;
    int bh = u >> 6, s = u & 63;
    int b = bh >> 4, h = bh & 15;
    int tid = threadIdx.x;
    if (tid < 64) zL[tid] = zx[((size_t)bh * 64 + s) * 64 + tid];
    __syncthreads();
    int row = tid & 63;
    bool isq = tid < 64;
    const bf16_t* src = (isq ? Qb : sK) +
                        ((size_t)b * 4096 + s * 64 + row) * 1024 + (size_t)h * 64;
    float acc = 0.f;
#pragma unroll
    for (int blk = 0; blk < 8; blk++) {
        bf16x8 v = *reinterpret_cast<const bf16x8*>(src + blk * 8);
#pragma unroll
        for (int j = 0; j < 8; j++) {
            float f = (float)v[j];
            float sg;
            if (isq) {
                sg = f > 0.f ? f + 1.f : __expf(f);
                sg = (float)(bf16_t)sg;   // match MFMA operand rounding
            } else {
                sg = f;                   // already sigma(k) in bf16
            }
            acc = __builtin_fmaf(sg, zL[blk * 8 + j], acc);
        }
    }
    float inv = 1.f / (acc + 1e-6f);
    float* dst = isq ? invq : invk;
    dst[((size_t)bh * 64 + s) * 64 + row] = inv;
}

// ---------------- k-side recurrence scan: 1 wave per block, no barriers ----------------
// grid 256: bh = blk & 63, cq = blk >> 6 (column quarter). M cols c0..c0+15 per block.
__global__ __launch_bounds__(64, 1) void scan_kernel(const bf16_t* __restrict__ sK,
                                                     const bf16_t* __restrict__ vTg,
                                                     const bf16_t* __restrict__ skTg,
                                                     const float* __restrict__ invk,
                                                     bf16_t* __restrict__ Msnap,
                                                     float* __restrict__ Mfin) {
    __shared__ bf16_t MbL[16 * 72];  // M^T slice: row = local col, elems = M row (swizzled)
    __shared__ bf16_t uTL[16 * 72];  // v^T slice -> u^T in place (swizzled)
    __shared__ float  ikL[64];

    int blk = blockIdx.x;
    int bh = blk & 63, cq = blk >> 6;
    int c0 = cq << 4;
    int b = bh >> 4, h = bh & 15;
    int lane = threadIdx.x;
    int lr = lane & 15, lk = lane >> 4;
    int vr = lane >> 2, vt0 = (lane & 3) << 4;

    size_t chbase = ((size_t)b * 4096) * 1024 + (size_t)h * 64;
    size_t stbase = (size_t)bh * 64 * 4096;

    auto swz = [](bf16_t* base, int row, int intra) -> bf16_t* {
        return (bf16_t*)((char*)base + row * 144 + (intra ^ ((row & 7) << 4)));
    };

    for (int i = lane; i < 16 * 72; i += 64) MbL[i] = (bf16_t)0.f;
    f32x4 Mreg[4];
#pragma unroll
    for (int rt = 0; rt < 4; rt++) Mreg[rt] = (f32x4){0.f, 0.f, 0.f, 0.f};

    bf16x8 cK[4][2], cT[4][2];
#pragma unroll
    for (int rt = 0; rt < 4; rt++)
#pragma unroll
        for (int ks = 0; ks < 2; ks++) {
            cK[rt][ks] = *reinterpret_cast<const bf16x8*>(
                sK + chbase + (size_t)(rt * 16 + lr) * 1024 + lk * 8 + ks * 32);
            cT[rt][ks] = *reinterpret_cast<const bf16x8*>(
                skTg + stbase + (size_t)(rt * 16 + lr) * 64 + lk * 8 + ks * 32);
        }
    {
        bf16x8 v0 = *reinterpret_cast<const bf16x8*>(vTg + chbase + (size_t)(c0 + vr) * 1024 + vt0);
        bf16x8 v1 = *reinterpret_cast<const bf16x8*>(vTg + chbase + (size_t)(c0 + vr) * 1024 + vt0 + 8);
        *reinterpret_cast<bf16x8*>(swz(uTL, vr, vt0 * 2))      = v0;
        *reinterpret_cast<bf16x8*>(swz(uTL, vr, vt0 * 2 + 16)) = v1;
        ikL[lane] = invk[(size_t)bh * 4096 + lane];
    }

    for (int s = 0; s < 64; s++) {
        bf16x8 nK[4][2], nT[4][2], nv0, nv1;
        float nik = 0.f;
        if (s < 63) {
            size_t vs2 = chbase + (size_t)(s + 1) * 65536;
            size_t sb2 = stbase + (size_t)(s + 1) * 4096;
#pragma unroll
            for (int rt = 0; rt < 4; rt++)
#pragma unroll
                for (int ks = 0; ks < 2; ks++) {
                    nK[rt][ks] = *reinterpret_cast<const bf16x8*>(
                        sK + vs2 + (size_t)(rt * 16 + lr) * 1024 + lk * 8 + ks * 32);
                    nT[rt][ks] = *reinterpret_cast<const bf16x8*>(
                        skTg + sb2 + (size_t)(rt * 16 + lr) * 64 + lk * 8 + ks * 32);
                }
            nv0 = *reinterpret_cast<const bf16x8*>(vTg + vs2 + (size_t)(c0 + vr) * 1024 + vt0);
            nv1 = *reinterpret_cast<const bf16x8*>(vTg + vs2 + (size_t)(c0 + vr) * 1024 + vt0 + 8);
            nik = invk[(size_t)bh * 4096 + (size_t)(s + 1) * 64 + lane];
        }

        // MFMA1: Y = sigma(k) @ M[:, c0:c0+16]
        bf16x8 mb0 = *reinterpret_cast<const bf16x8*>(swz(MbL, lr, lk * 16));
        bf16x8 mb1 = *reinterpret_cast<const bf16x8*>(swz(MbL, lr, lk * 16 + 64));
        f32x4 Y[4];
#pragma unroll
        for (int rt = 0; rt < 4; rt++) {
            Y[rt] = (f32x4){0.f, 0.f, 0.f, 0.f};
            Y[rt] = __builtin_amdgcn_mfma_f32_16x16x32_bf16(cK[rt][0], mb0, Y[rt], 0, 0, 0);
            Y[rt] = __builtin_amdgcn_mfma_f32_16x16x32_bf16(cK[rt][1], mb1, Y[rt], 0, 0, 0);
        }

        // epilogue: u = v - Y*invk[t], in place in uTL
#pragma unroll
        for (int rt = 0; rt < 4; rt++) {
            bf16x4 vv = *reinterpret_cast<const bf16x4*>(swz(uTL, lr, rt * 32 + lk * 8));
            bf16x4 uu;
#pragma unroll
            for (int j = 0; j < 4; j++) {
                float ik = ikL[rt * 16 + lk * 4 + j];
                uu[j] = (bf16_t)((float)vv[j] - Y[rt][j] * ik);
            }
            *reinterpret_cast<bf16x4*>(swz(uTL, lr, rt * 32 + lk * 8)) = uu;
        }

        // MFMA2: M[:, c0:+16] += sigma(k)^T @ u
        bf16x8 ub0 = *reinterpret_cast<const bf16x8*>(swz(uTL, lr, lk * 16));
        bf16x8 ub1 = *reinterpret_cast<const bf16x8*>(swz(uTL, lr, lk * 16 + 64));
#pragma unroll
        for (int rt = 0; rt < 4; rt++) {
            Mreg[rt] = __builtin_amdgcn_mfma_f32_16x16x32_bf16(cT[rt][0], ub0, Mreg[rt], 0, 0, 0);
            Mreg[rt] = __builtin_amdgcn_mfma_f32_16x16x32_bf16(cT[rt][1], ub1, Mreg[rt], 0, 0, 0);
        }

        // refresh bf16 M^T slice + snapshot store (M_{s+1}, consumed by combine at seg s+1)
#pragma unroll
        for (int rt = 0; rt < 4; rt++) {
            bf16x4 mp;
#pragma unroll
            for (int j = 0; j < 4; j++) mp[j] = (bf16_t)Mreg[rt][j];
            *reinterpret_cast<bf16x4*>(swz(MbL, lr, rt * 32 + lk * 8)) = mp;
            if (s < 63)
                *reinterpret_cast<bf16x4*>(
                    Msnap + (((size_t)bh * 64 + s + 1) * 64 + c0 + lr) * 64 + rt * 16 + lk * 4) = mp;
        }

        if (s < 63) {
#pragma unroll
            for (int rt = 0; rt < 4; rt++)
#pragma unroll
                for (int ks = 0; ks < 2; ks++) { cK[rt][ks] = nK[rt][ks]; cT[rt][ks] = nT[rt][ks]; }
            *reinterpret_cast<bf16x8*>(swz(uTL, vr, vt0 * 2))      = nv0;
            *reinterpret_cast<bf16x8*>(swz(uTL, vr, vt0 * 2 + 16)) = nv1;
            ikL[lane] = nik;
        }
    }

    // final M slice (f32)
#pragma unroll
    for (int rt = 0; rt < 4; rt++)
#pragma unroll
        for (int j = 0; j < 4; j++)
            Mfin[(size_t)bh * 4096 + (size_t)(rt * 16 + lk * 4 + j) * 64 + c0 + lr] = Mreg[rt][j];
}

// ---------------- parallel combine: A_mem from snapshots, beta-blend with A_dot ----------------
__global__ __launch_bounds__(256) void combine_kernel(const bf16_t* __restrict__ Qb,
                                                      const bf16_t* __restrict__ Msnap,
                                                      const bf16_t* __restrict__ Adot,
                                                      const float* __restrict__ invq,
                                                      const float* __restrict__ beta_param,
                                                      bf16_t* __restrict__ Op) {
    __shared__ bf16_t oS[64 * 72];
    __shared__ bf16_t adS[64 * 72];
    __shared__ float  iq[64];

    int u = blockIdx.x;
    int bh = u >> 6, s = u & 63;
    int b = bh >> 4, h = bh & 15;
    int tid = threadIdx.x;
    int w = tid >> 6, lane = tid & 63;
    int lr = lane & 15, lk = lane >> 4;
    int r = tid >> 2, c0 = (tid & 3) << 4;

    size_t vseg = ((size_t)b * 4096 + s * 64) * 1024 + (size_t)h * 64;
    size_t sb = ((size_t)bh * 64 + s) * 4096;   // element base of this (bh,s) 64x64 tile
    size_t ib = ((size_t)bh * 64 + s) * 64;     // element base of this (bh,s) 64-vector

    float beta = 1.f / (1.f + __expf(-beta_param[h]));
    float omb = 1.f - beta;

    // stage A_dot + invq
    *reinterpret_cast<bf16x8*>(&adS[r * 72 + c0]) =
        *reinterpret_cast<const bf16x8*>(Adot + sb + (size_t)r * 64 + c0);
    *reinterpret_cast<bf16x8*>(&adS[r * 72 + c0 + 8]) =
        *reinterpret_cast<const bf16x8*>(Adot + sb + (size_t)r * 64 + c0 + 8);
    if (tid < 64) iq[tid] = invq[ib + tid];

    f32x4 Y[4];
#pragma unroll
    for (int ct = 0; ct < 4; ct++) Y[ct] = (f32x4){0.f, 0.f, 0.f, 0.f};
    if (s > 0) {
        bf16x8 aq[2];
#pragma unroll
        for (int ks = 0; ks < 2; ks++)
            aq[ks] = sigma8(*reinterpret_cast<const bf16x8*>(
                Qb + vseg + (size_t)(w * 16 + lr) * 1024 + lk * 8 + ks * 32));
#pragma unroll
        for (int ct = 0; ct < 4; ct++)
#pragma unroll
            for (int ks = 0; ks < 2; ks++) {
                bf16x8 bfrag = *reinterpret_cast<const bf16x8*>(
                    Msnap + sb + (size_t)(ct * 16 + lr) * 64 + lk * 8 + ks * 32);
                Y[ct] = __builtin_amdgcn_mfma_f32_16x16x32_bf16(aq[ks], bfrag, Y[ct], 0, 0, 0);
            }
    }
    __syncthreads();

    // blend into oS
#pragma unroll
    for (int ct = 0; ct < 4; ct++) {
        int colc = ct * 16 + lr;
#pragma unroll
        for (int j = 0; j < 4; j++) {
            int t = w * 16 + lk * 4 + j;
            float o = beta * (Y[ct][j] * iq[t]) + omb * (float)adS[t * 72 + colc];
            oS[t * 72 + colc] = (bf16_t)o;
        }
    }
    __syncthreads();

    *reinterpret_cast<bf16x8*>(Op + vseg + (size_t)r * 1024 + c0) =
        *reinterpret_cast<const bf16x8*>(&oS[r * 72 + c0]);
    *reinterpret_cast<bf16x8*>(Op + vseg + (size_t)r * 1024 + c0 + 8) =
        *reinterpret_cast<const bf16x8*>(&oS[r * 72 + c0 + 8]);
}

// ---------------- final means over batch ----------------
__global__ __launch_bounds__(256) void mean_kernel(const float* __restrict__ Mfin,
                                                   const float* __restrict__ zfin,
                                                   float* __restrict__ out) {
    int idx = blockIdx.x * 256 + threadIdx.x;
    if (idx < 65536) {
        out[16777216 + idx] = 0.25f * (Mfin[idx] + Mfin[idx + 65536] +
                                       Mfin[idx + 131072] + Mfin[idx + 196608]);
    } else if (idx < 66560) {
        int j = idx - 65536;
        out[16842752 + j] = 0.25f * (zfin[j] + zfin[j + 1024] + zfin[j + 2048] + zfin[j + 3072]);
    }
}

extern "C" void kernel_launch(void* const* d_in, const int* in_sizes, int n_in,
                              void* d_out, int out_size, void* d_ws, size_t ws_size,
                              hipStream_t stream) {
    const float* x      = (const float*)d_in[0];
    const float* Wq     = (const float*)d_in[1];
    const float* Wk     = (const float*)d_in[2];
    const float* Wv     = (const float*)d_in[3];
    const float* Wo     = (const float*)d_in[4];
    const float* beta_p = (const float*)d_in[5];
    float* out = (float*)d_out;
    char* ws = (char*)d_ws;

    const size_t NX = 16777216ull;
    const size_t NW = 1048576ull;

    bf16_t* xb   = (bf16_t*)ws;
    bf16_t* Adot = xb;                                  // alias (xb dead after QKV GEMMs)
    bf16_t* Wqb  = (bf16_t*)(ws + 33554432);
    bf16_t* Wkb  = (bf16_t*)(ws + 35651584);
    bf16_t* Wvb  = (bf16_t*)(ws + 37748736);
    bf16_t* Wob  = (bf16_t*)(ws + 39845888);
    bf16_t* Qb   = (bf16_t*)(ws + 41943040);
    bf16_t* Kb   = (bf16_t*)(ws + 75497472);            // becomes sigma(k) after attn
    bf16_t* Vb   = (bf16_t*)(ws + 109051904);           // becomes v^T after attn
    bf16_t* skT  = (bf16_t*)(ws + 142606336);
    bf16_t* Op   = (bf16_t*)(ws + 176160768);
    float*  csum = (float*)(ws + 209715200);
    float*  zx   = (float*)(ws + 210763776);
    float*  invq = (float*)(ws + 211812352);
    float*  invk = (float*)(ws + 212860928);
    float*  Mfin = (float*)(ws + 213909504);
    float*  zfin = (float*)(ws + 214958080);
    bf16_t* Msnap = (bf16_t*)d_out;                     // 32MB of the 67MB output buffer (dead until final GEMM)

    cast_bf16_kernel<<<dim3(16384), dim3(256), 0, stream>>>(x, xb, (int)(NX / 4));
    cast_bf16_kernel<<<dim3(1024), dim3(256), 0, stream>>>(Wq, Wqb, (int)(NW / 4));
    cast_bf16_kernel<<<dim3(1024), dim3(256), 0, stream>>>(Wk, Wkb, (int)(NW / 4));
    cast_bf16_kernel<<<dim3(1024), dim3(256), 0, stream>>>(Wv, Wvb, (int)(NW / 4));
    cast_bf16_kernel<<<dim3(1024), dim3(256), 0, stream>>>(Wo, Wob, (int)(NW / 4));

    gemm_bt<1><<<dim3(1024), dim3(256), 0, stream>>>(xb, Wqb, (void*)Qb, 16384, 1024, 1024);
    gemm_bt<1><<<dim3(1024), dim3(256), 0, stream>>>(xb, Wkb, (void*)Kb, 16384, 1024, 1024);
    gemm_bt<1><<<dim3(1024), dim3(256), 0, stream>>>(xb, Wvb, (void*)Vb, 16384, 1024, 1024);

    attn_kernel<<<dim3(4096), dim3(256), 0, stream>>>(Qb, Kb, Vb, skT, csum, Adot);
    zprefix_kernel<<<dim3(64), dim3(64), 0, stream>>>(csum, zx, zfin);
    denom_kernel<<<dim3(4096), dim3(128), 0, stream>>>(Qb, Kb, zx, invq, invk);
    scan_kernel<<<dim3(256), dim3(64), 0, stream>>>(Kb, Vb, skT, invk, Msnap, Mfin);
    combine_kernel<<<dim3(4096), dim3(256), 0, stream>>>(Qb, Msnap, Adot, invq, beta_p, Op);

    gemm_bt<0><<<dim3(1024), dim3(256), 0, stream>>>(Op, Wob, d_out, 16384, 1024, 1024);
    mean_kernel<<<dim3(260), dim3(256), 0, stream>>>(Mfin, zfin, out);
}

// Round 6
// 403.561 us; speedup vs baseline: 15.7949x; 1.0241x over previous
//
#include <hip/hip_runtime.h>

typedef __bf16 bf16_t;
typedef __bf16 bf16x8 __attribute__((ext_vector_type(8)));
typedef __bf16 bf16x4 __attribute__((ext_vector_type(4)));
typedef float  f32x4  __attribute__((ext_vector_type(4)));

__device__ __forceinline__ void gload16(const bf16_t* g, bf16_t* l) {
    __builtin_amdgcn_global_load_lds(
        (const __attribute__((address_space(1))) void*)(g),
        (__attribute__((address_space(3))) void*)(l), 16, 0, 0);
}

// ---------------- f32 -> bf16 cast ----------------
__global__ __launch_bounds__(256) void cast_bf16_kernel(const float* __restrict__ in,
                                                        bf16_t* __restrict__ out, int n4) {
    int i = blockIdx.x * 256 + threadIdx.x;
    if (i >= n4) return;
    f32x4 v = *reinterpret_cast<const f32x4*>(in + (size_t)i * 4);
    bf16x4 o;
    o[0] = (bf16_t)v[0]; o[1] = (bf16_t)v[1]; o[2] = (bf16_t)v[2]; o[3] = (bf16_t)v[3];
    *reinterpret_cast<bf16x4*>(out + (size_t)i * 4) = o;
}

__device__ __forceinline__ bf16x8 sigma8(bf16x8 x) {
    bf16x8 o;
#pragma unroll
    for (int j = 0; j < 8; j++) {
        float f = (float)x[j];
        float sg = f > 0.f ? f + 1.f : __expf(f);
        o[j] = (bf16_t)sg;
    }
    return o;
}

// ---------------- 256x256 GEMM, BK=32, 4-slot LDS ring, counted vmcnt ----------------
// C = A (MxK) * B^T (B is NxK row-major). 512 threads = 8 waves (2m x 4n).
template <int OUT_BF16>
__global__ __launch_bounds__(512, 2) void gemm256(const bf16_t* __restrict__ A,
                                                  const bf16_t* __restrict__ Bm,
                                                  void* __restrict__ Cv,
                                                  int M, int N, int K) {
    __shared__ bf16_t As[4][256 * 32];
    __shared__ bf16_t Bs[4][256 * 32];

    // XCD-aware mapping: XCD x covers bm in [x*8, x*8+8) so A-panels L2-hit per XCD.
    int bid = blockIdx.x;
    int xq = bid & 7, jq = bid >> 3;
    int bm = xq * 8 + (jq >> 2), bn = jq & 3;

    int tid = threadIdx.x;
    int w = tid >> 6, lane = tid & 63;
    int wm = w >> 2, wn = w & 3;
    int lr = lane & 15, lk = lane >> 4;

    // ---- staging addressing (pre-swizzled global source, linear LDS dest) ----
    int srow = lane >> 2;                      // 0..15 within a 16-row call
    int schunk = (lane & 3) ^ (srow & 3);      // logical 8-elem chunk
    const bf16_t* gA0 = A  + (size_t)(bm * 256 + w * 32 + srow) * K + schunk * 8;
    const bf16_t* gA1 = gA0 + (size_t)16 * K;
    const bf16_t* gB0 = Bm + (size_t)(bn * 256 + w * 32 + srow) * K + schunk * 8;
    const bf16_t* gB1 = gB0 + (size_t)16 * K;
    int lO0 = (w * 32) * 32 + lane * 8;        // element offset in slot
    int lO1 = (w * 32 + 16) * 32 + lane * 8;

    // ---- fragment read byte offsets (swizzled) ----
    int chunkb = (lk ^ (lr & 3)) << 4;
    int aoff[8], boff[4];
#pragma unroll
    for (int mi = 0; mi < 8; mi++) aoff[mi] = (wm * 128 + mi * 16 + lr) * 64 + chunkb;
#pragma unroll
    for (int ni = 0; ni < 4; ni++) boff[ni] = (wn * 64 + ni * 16 + lr) * 64 + chunkb;

    f32x4 acc[8][4];
#pragma unroll
    for (int mi = 0; mi < 8; mi++)
#pragma unroll
        for (int ni = 0; ni < 4; ni++) acc[mi][ni] = (f32x4){0.f, 0.f, 0.f, 0.f};

    const int NT = K >> 5;

    auto STAGE = [&](int t) {
        int slot = t & 3;
        size_t ko = (size_t)t * 32;
        gload16(gA0 + ko, &As[slot][lO0]);
        gload16(gA1 + ko, &As[slot][lO1]);
        gload16(gB0 + ko, &Bs[slot][lO0]);
        gload16(gB1 + ko, &Bs[slot][lO1]);
    };

    auto COMPUTE = [&](int t) {
        const char* pa = (const char*)(&As[t & 3][0]);
        const char* pb = (const char*)(&Bs[t & 3][0]);
        bf16x8 af[8], bfr[4];
#pragma unroll
        for (int mi = 0; mi < 8; mi++)
            af[mi] = *reinterpret_cast<const bf16x8*>(pa + aoff[mi]);
#pragma unroll
        for (int ni = 0; ni < 4; ni++)
            bfr[ni] = *reinterpret_cast<const bf16x8*>(pb + boff[ni]);
        asm volatile("s_waitcnt lgkmcnt(0)" ::: "memory");
        __builtin_amdgcn_sched_barrier(0);
        __builtin_amdgcn_s_barrier();          // readers done -> slot reusable next iter
        __builtin_amdgcn_sched_barrier(0);
#pragma unroll
        for (int mi = 0; mi < 8; mi++)
#pragma unroll
            for (int ni = 0; ni < 4; ni++)
                acc[mi][ni] = __builtin_amdgcn_mfma_f32_16x16x32_bf16(af[mi], bfr[ni], acc[mi][ni], 0, 0, 0);
    };

    // prologue: stage tiles 0..2 (12 loads in flight per wave)
    STAGE(0); STAGE(1); STAGE(2);

#pragma unroll 1
    for (int t = 0; t + 3 < NT; ++t) {
        STAGE(t + 3);                           // 16 in flight
        asm volatile("s_waitcnt vmcnt(12)" ::: "memory");   // tile t landed (own loads)
        __builtin_amdgcn_sched_barrier(0);
        __builtin_amdgcn_s_barrier();           // all waves' tile-t loads landed
        __builtin_amdgcn_sched_barrier(0);
        COMPUTE(t);
    }
    asm volatile("s_waitcnt vmcnt(8)" ::: "memory");
    __builtin_amdgcn_sched_barrier(0);
    __builtin_amdgcn_s_barrier();
    __builtin_amdgcn_sched_barrier(0);
    COMPUTE(NT - 3);
    asm volatile("s_waitcnt vmcnt(4)" ::: "memory");
    __builtin_amdgcn_sched_barrier(0);
    __builtin_amdgcn_s_barrier();
    __builtin_amdgcn_sched_barrier(0);
    COMPUTE(NT - 2);
    asm volatile("s_waitcnt vmcnt(0)" ::: "memory");
    __builtin_amdgcn_sched_barrier(0);
    __builtin_amdgcn_s_barrier();
    __builtin_amdgcn_sched_barrier(0);
    COMPUTE(NT - 1);

    int row0 = bm * 256 + wm * 128 + lk * 4;
    int col0 = bn * 256 + wn * 64 + lr;
#pragma unroll
    for (int mi = 0; mi < 8; mi++)
#pragma unroll
        for (int ni = 0; ni < 4; ni++)
#pragma unroll
            for (int jj = 0; jj < 4; jj++) {
                size_t idx = (size_t)(row0 + mi * 16 + jj) * N + (col0 + ni * 16);
                float v = acc[mi][ni][jj];
                if (OUT_BF16) reinterpret_cast<bf16_t*>(Cv)[idx] = (bf16_t)v;
                else          reinterpret_cast<float*>(Cv)[idx]  = v;
            }
}

// ---------------- parallel local attention; writes sigma(k) in place over Kb,
// v^T in place over Vb, sigma(k)^T dense, column sums, A_dot ----------------
__global__ __launch_bounds__(256) void attn_kernel(const bf16_t* __restrict__ Qb,
                                                   bf16_t* __restrict__ Kb,
                                                   bf16_t* __restrict__ Vb,
                                                   bf16_t* __restrict__ skTg,
                                                   float* __restrict__ csum,
                                                   bf16_t* __restrict__ Adot) {
    __shared__ bf16_t kS[64 * 72];
    __shared__ bf16_t vS[64 * 72];
    __shared__ bf16_t skT[64 * 72];
    __shared__ bf16_t vT[64 * 72];
    __shared__ bf16_t pS[64 * 72];
    __shared__ float  scr[64 * 68];

    int u = blockIdx.x;
    int bh = u >> 6, s = u & 63;
    int b = bh >> 4, h = bh & 15;
    int tid = threadIdx.x;
    int w = tid >> 6, lane = tid & 63;
    int lr = lane & 15, lk = lane >> 4;
    int r = tid >> 2, qd = tid & 3, c0 = qd << 4;

    size_t vseg = ((size_t)b * 4096 + s * 64) * 1024 + (size_t)h * 64;
    size_t sb = ((size_t)bh * 64 + s) * 4096;

    {
        bf16x8 k0 = *reinterpret_cast<const bf16x8*>(Kb + vseg + (size_t)r * 1024 + c0);
        bf16x8 k1 = *reinterpret_cast<const bf16x8*>(Kb + vseg + (size_t)r * 1024 + c0 + 8);
        bf16x8 v0 = *reinterpret_cast<const bf16x8*>(Vb + vseg + (size_t)r * 1024 + c0);
        bf16x8 v1 = *reinterpret_cast<const bf16x8*>(Vb + vseg + (size_t)r * 1024 + c0 + 8);
        *reinterpret_cast<bf16x8*>(&kS[r * 72 + c0])     = k0;
        *reinterpret_cast<bf16x8*>(&kS[r * 72 + c0 + 8]) = k1;
        *reinterpret_cast<bf16x8*>(&vS[r * 72 + c0])     = v0;
        *reinterpret_cast<bf16x8*>(&vS[r * 72 + c0 + 8]) = v1;
        bf16x8 s0 = sigma8(k0), s1 = sigma8(k1);
        *reinterpret_cast<bf16x8*>(Kb + vseg + (size_t)r * 1024 + c0)     = s0;
        *reinterpret_cast<bf16x8*>(Kb + vseg + (size_t)r * 1024 + c0 + 8) = s1;
#pragma unroll
        for (int j = 0; j < 8; j++) {
            skT[(c0 + j) * 72 + r]     = s0[j];
            skT[(c0 + 8 + j) * 72 + r] = s1[j];
            vT[(c0 + j) * 72 + r]      = v0[j];
            vT[(c0 + 8 + j) * 72 + r]  = v1[j];
        }
    }
    __syncthreads();

    if (tid < 64) {
        float acc = 0.f;
#pragma unroll 8
        for (int t = 0; t < 64; t++) acc += (float)skT[tid * 72 + t];
        csum[((size_t)bh * 64 + s) * 64 + tid] = acc;
    }
    *reinterpret_cast<bf16x8*>(skTg + sb + (size_t)r * 64 + c0) =
        *reinterpret_cast<const bf16x8*>(&skT[r * 72 + c0]);
    *reinterpret_cast<bf16x8*>(skTg + sb + (size_t)r * 64 + c0 + 8) =
        *reinterpret_cast<const bf16x8*>(&skT[r * 72 + c0 + 8]);
    *reinterpret_cast<bf16x8*>(Vb + vseg + (size_t)r * 1024 + c0) =
        *reinterpret_cast<const bf16x8*>(&vT[r * 72 + c0]);
    *reinterpret_cast<bf16x8*>(Vb + vseg + (size_t)r * 1024 + c0 + 8) =
        *reinterpret_cast<const bf16x8*>(&vT[r * 72 + c0 + 8]);

    {
        bf16x8 aq[2];
#pragma unroll
        for (int ks = 0; ks < 2; ks++)
            aq[ks] = *reinterpret_cast<const bf16x8*>(Qb + vseg + (size_t)(w * 16 + lr) * 1024 + lk * 8 + ks * 32);
        f32x4 sc[4];
#pragma unroll
        for (int ct = 0; ct < 4; ct++) {
            sc[ct] = (f32x4){0.f, 0.f, 0.f, 0.f};
#pragma unroll
            for (int ks = 0; ks < 2; ks++) {
                bf16x8 bfrag = *reinterpret_cast<const bf16x8*>(&kS[(ct * 16 + lr) * 72 + lk * 8 + ks * 32]);
                sc[ct] = __builtin_amdgcn_mfma_f32_16x16x32_bf16(aq[ks], bfrag, sc[ct], 0, 0, 0);
            }
        }
#pragma unroll
        for (int ct = 0; ct < 4; ct++)
#pragma unroll
            for (int j = 0; j < 4; j++)
                scr[(w * 16 + lk * 4 + j) * 68 + ct * 16 + lr] = sc[ct][j] * 0.125f;
    }
    __syncthreads();

    {
        float p[16];
        float mx = -3.4e38f;
        const float* srow_p = &scr[r * 68 + c0];
#pragma unroll
        for (int i = 0; i < 16; i++) {
            int c = c0 + i;
            float v = (c <= r) ? srow_p[i] : -3.4e38f;
            p[i] = v;
            mx = fmaxf(mx, v);
        }
        mx = fmaxf(mx, __shfl_xor(mx, 1));
        mx = fmaxf(mx, __shfl_xor(mx, 2));
        float sum = 0.f;
#pragma unroll
        for (int i = 0; i < 16; i++) {
            int c = c0 + i;
            float e = (c <= r) ? __expf(p[i] - mx) : 0.f;
            p[i] = e;
            sum += e;
        }
        sum += __shfl_xor(sum, 1);
        sum += __shfl_xor(sum, 2);
        float inv = 1.f / sum;
        bf16x8 p0, p1;
#pragma unroll
        for (int j = 0; j < 8; j++) {
            p0[j] = (bf16_t)(p[j] * inv);
            p1[j] = (bf16_t)(p[8 + j] * inv);
        }
        *reinterpret_cast<bf16x8*>(&pS[r * 72 + c0])     = p0;
        *reinterpret_cast<bf16x8*>(&pS[r * 72 + c0 + 8]) = p1;
    }
    __syncthreads();

    {
        f32x4 ad[4];
#pragma unroll
        for (int ct = 0; ct < 4; ct++) {
            ad[ct] = (f32x4){0.f, 0.f, 0.f, 0.f};
#pragma unroll
            for (int ks = 0; ks < 2; ks++) {
                bf16x8 afrag = *reinterpret_cast<const bf16x8*>(&pS[(w * 16 + lr) * 72 + lk * 8 + ks * 32]);
                bf16x8 bfrag = *reinterpret_cast<const bf16x8*>(&vT[(ct * 16 + lr) * 72 + lk * 8 + ks * 32]);
                ad[ct] = __builtin_amdgcn_mfma_f32_16x16x32_bf16(afrag, bfrag, ad[ct], 0, 0, 0);
            }
        }
#pragma unroll
        for (int ct = 0; ct < 4; ct++)
#pragma unroll
            for (int j = 0; j < 4; j++)
                kS[(w * 16 + lk * 4 + j) * 72 + ct * 16 + lr] = (bf16_t)ad[ct][j];
    }
    __syncthreads();
    *reinterpret_cast<bf16x8*>(Adot + sb + (size_t)r * 64 + c0) =
        *reinterpret_cast<const bf16x8*>(&kS[r * 72 + c0]);
    *reinterpret_cast<bf16x8*>(Adot + sb + (size_t)r * 64 + c0 + 8) =
        *reinterpret_cast<const bf16x8*>(&kS[r * 72 + c0 + 8]);
}

// ---------------- z prefix over segments ----------------
__global__ __launch_bounds__(64) void zprefix_kernel(const float* __restrict__ csum,
                                                     float* __restrict__ zx,
                                                     float* __restrict__ zfin) {
    int bh = blockIdx.x;
    int d = threadIdx.x;
    float z = 0.f;
    for (int s = 0; s < 64; s++) {
        size_t o = ((size_t)bh * 64 + s) * 64 + d;
        zx[o] = z;
        z += csum[o];
    }
    zfin[bh * 64 + d] = z;
}

// ---------------- denominators 1/(sigma . z + eps) ----------------
__global__ __launch_bounds__(128) void denom_kernel(const bf16_t* __restrict__ Qb,
                                                    const bf16_t* __restrict__ sK,
                                                    const float* __restrict__ zx,
                                                    float* __restrict__ invq,
                                                    float* __restrict__ invk) {
    __shared__ float zL[64];
    int u = blockIdx.x;
    int bh = u >> 6, s = u & 63;
    int b = bh >> 4, h = bh & 15;
    int tid = threadIdx.x;
    if (tid < 64) zL[tid] = zx[((size_t)bh * 64 + s) * 64 + tid];
    __syncthreads();
    int row = tid & 63;
    bool isq = tid < 64;
    const bf16_t* src = (isq ? Qb : sK) +
                        ((size_t)b * 4096 + s * 64 + row) * 1024 + (size_t)h * 64;
    float acc = 0.f;
#pragma unroll
    for (int blk = 0; blk < 8; blk++) {
        bf16x8 v = *reinterpret_cast<const bf16x8*>(src + blk * 8);
#pragma unroll
        for (int j = 0; j < 8; j++) {
            float f = (float)v[j];
            float sg;
            if (isq) {
                sg = f > 0.f ? f + 1.f : __expf(f);
                sg = (float)(bf16_t)sg;
            } else {
                sg = f;
            }
            acc = __builtin_fmaf(sg, zL[blk * 8 + j], acc);
        }
    }
    float inv = 1.f / (acc + 1e-6f);
    float* dst = isq ? invq : invk;
    dst[((size_t)bh * 64 + s) * 64 + row] = inv;
}

// ---------------- k-side recurrence scan: 1 wave/block, no barriers, depth-2 prefetch ----
__global__ __launch_bounds__(64, 1) void scan_kernel(const bf16_t* __restrict__ sK,
                                                     const bf16_t* __restrict__ vTg,
                                                     const bf16_t* __restrict__ skTg,
                                                     const float* __restrict__ invk,
                                                     bf16_t* __restrict__ Msnap,
                                                     float* __restrict__ Mfin) {
    __shared__ bf16_t MbL[16 * 72];
    __shared__ bf16_t uTL[16 * 72];
    __shared__ float  ikL[64];

    int blk = blockIdx.x;
    int bh = blk & 63, cq = blk >> 6;
    int c0 = cq << 4;
    int b = bh >> 4, h = bh & 15;
    int lane = threadIdx.x;
    int lr = lane & 15, lk = lane >> 4;
    int vr = lane >> 2, vt0 = (lane & 3) << 4;

    size_t chbase = ((size_t)b * 4096) * 1024 + (size_t)h * 64;
    size_t stbase = (size_t)bh * 64 * 4096;

    auto swz = [](bf16_t* base, int row, int intra) -> bf16_t* {
        return (bf16_t*)((char*)base + row * 144 + (intra ^ ((row & 7) << 4)));
    };

    for (int i = lane; i < 16 * 72; i += 64) MbL[i] = (bf16_t)0.f;
    f32x4 Mreg[4];
#pragma unroll
    for (int rt = 0; rt < 4; rt++) Mreg[rt] = (f32x4){0.f, 0.f, 0.f, 0.f};

    bf16x8 Ka[4][2], Ta[4][2], Kb_[4][2], Tb_[4][2];
    bf16x8 vA0, vA1, vB0, vB1;
    float ikA = 0.f, ikB = 0.f;

    // ---- prologue ----
#pragma unroll
    for (int rt = 0; rt < 4; rt++)
#pragma unroll
        for (int ks = 0; ks < 2; ks++) {
            Ka[rt][ks] = *reinterpret_cast<const bf16x8*>(
                sK + chbase + (size_t)(rt * 16 + lr) * 1024 + lk * 8 + ks * 32);
            Ta[rt][ks] = *reinterpret_cast<const bf16x8*>(
                skTg + stbase + (size_t)(rt * 16 + lr) * 64 + lk * 8 + ks * 32);
            Kb_[rt][ks] = *reinterpret_cast<const bf16x8*>(
                sK + chbase + 65536 + (size_t)(rt * 16 + lr) * 1024 + lk * 8 + ks * 32);
            Tb_[rt][ks] = *reinterpret_cast<const bf16x8*>(
                skTg + stbase + 4096 + (size_t)(rt * 16 + lr) * 64 + lk * 8 + ks * 32);
        }
    {
        bf16x8 v0 = *reinterpret_cast<const bf16x8*>(vTg + chbase + (size_t)(c0 + vr) * 1024 + vt0);
        bf16x8 v1 = *reinterpret_cast<const bf16x8*>(vTg + chbase + (size_t)(c0 + vr) * 1024 + vt0 + 8);
        *reinterpret_cast<bf16x8*>(swz(uTL, vr, vt0 * 2))      = v0;
        *reinterpret_cast<bf16x8*>(swz(uTL, vr, vt0 * 2 + 16)) = v1;
        ikL[lane] = invk[(size_t)bh * 4096 + lane];
        vB0 = *reinterpret_cast<const bf16x8*>(vTg + chbase + 65536 + (size_t)(c0 + vr) * 1024 + vt0);
        vB1 = *reinterpret_cast<const bf16x8*>(vTg + chbase + 65536 + (size_t)(c0 + vr) * 1024 + vt0 + 8);
        ikB = invk[(size_t)bh * 4096 + 64 + lane];
    }

#define SCAN_STEP(S, CK, CT, NV0, NV1, NIK, SV0, SV1, SIK)                              \
    {                                                                                   \
        bf16x8 mb0 = *reinterpret_cast<const bf16x8*>(swz(MbL, lr, lk * 16));           \
        bf16x8 mb1 = *reinterpret_cast<const bf16x8*>(swz(MbL, lr, lk * 16 + 64));      \
        f32x4 Y[4];                                                                     \
        _Pragma("unroll")                                                               \
        for (int rt = 0; rt < 4; rt++) {                                                \
            Y[rt] = (f32x4){0.f, 0.f, 0.f, 0.f};                                        \
            Y[rt] = __builtin_amdgcn_mfma_f32_16x16x32_bf16(CK[rt][0], mb0, Y[rt], 0, 0, 0); \
            Y[rt] = __builtin_amdgcn_mfma_f32_16x16x32_bf16(CK[rt][1], mb1, Y[rt], 0, 0, 0); \
        }                                                                               \
        _Pragma("unroll")                                                               \
        for (int rt = 0; rt < 4; rt++) {                                                \
            bf16x4 vv = *reinterpret_cast<const bf16x4*>(swz(uTL, lr, rt * 32 + lk * 8)); \
            bf16x4 uu;                                                                  \
            _Pragma("unroll")                                                           \
            for (int j = 0; j < 4; j++) {                                               \
                float ik = ikL[rt * 16 + lk * 4 + j];                                   \
                uu[j] = (bf16_t)((float)vv[j] - Y[rt][j] * ik);                         \
            }                                                                           \
            *reinterpret_cast<bf16x4*>(swz(uTL, lr, rt * 32 + lk * 8)) = uu;            \
        }                                                                               \
        bf16x8 ub0 = *reinterpret_cast<const bf16x8*>(swz(uTL, lr, lk * 16));           \
        bf16x8 ub1 = *reinterpret_cast<const bf16x8*>(swz(uTL, lr, lk * 16 + 64));      \
        _Pragma("unroll")                                                               \
        for (int rt = 0; rt < 4; rt++) {                                                \
            Mreg[rt] = __builtin_amdgcn_mfma_f32_16x16x32_bf16(CT[rt][0], ub0, Mreg[rt], 0, 0, 0); \
            Mreg[rt] = __builtin_amdgcn_mfma_f32_16x16x32_bf16(CT[rt][1], ub1, Mreg[rt], 0, 0, 0); \
        }                                                                               \
        _Pragma("unroll")                                                               \
        for (int rt = 0; rt < 4; rt++) {                                                \
            bf16x4 mp;                                                                  \
            _Pragma("unroll")                                                           \
            for (int j = 0; j < 4; j++) mp[j] = (bf16_t)Mreg[rt][j];                    \
            *reinterpret_cast<bf16x4*>(swz(MbL, lr, rt * 32 + lk * 8)) = mp;            \
            if ((S) < 63)                                                               \
                *reinterpret_cast<bf16x4*>(                                             \
                    Msnap + (((size_t)bh * 64 + (S) + 1) * 64 + c0 + lr) * 64 + rt * 16 + lk * 4) = mp; \
        }                                                                               \
        if ((S) < 62) {                                                                 \
            size_t vs2 = chbase + (size_t)((S) + 2) * 65536;                            \
            size_t sb2 = stbase + (size_t)((S) + 2) * 4096;                             \
            _Pragma("unroll")                                                           \
            for (int rt = 0; rt < 4; rt++) {                                            \
                CK[rt][0] = *reinterpret_cast<const bf16x8*>(                           \
                    sK + vs2 + (size_t)(rt * 16 + lr) * 1024 + lk * 8);                 \
                CK[rt][1] = *reinterpret_cast<const bf16x8*>(                           \
                    sK + vs2 + (size_t)(rt * 16 + lr) * 1024 + lk * 8 + 32);            \
                CT[rt][0] = *reinterpret_cast<const bf16x8*>(                           \
                    skTg + sb2 + (size_t)(rt * 16 + lr) * 64 + lk * 8);                 \
                CT[rt][1] = *reinterpret_cast<const bf16x8*>(                           \
                    skTg + sb2 + (size_t)(rt * 16 + lr) * 64 + lk * 8 + 32);            \
            }                                                                           \
            NV0 = *reinterpret_cast<const bf16x8*>(vTg + vs2 + (size_t)(c0 + vr) * 1024 + vt0);      \
            NV1 = *reinterpret_cast<const bf16x8*>(vTg + vs2 + (size_t)(c0 + vr) * 1024 + vt0 + 8);  \
            NIK = invk[(size_t)bh * 4096 + (size_t)((S) + 2) * 64 + lane];              \
        }                                                                               \
        if ((S) < 63) {                                                                 \
            *reinterpret_cast<bf16x8*>(swz(uTL, vr, vt0 * 2))      = SV0;               \
            *reinterpret_cast<bf16x8*>(swz(uTL, vr, vt0 * 2 + 16)) = SV1;               \
            ikL[lane] = SIK;                                                            \
        }                                                                               \
    }

#pragma unroll 1
    for (int s2 = 0; s2 < 64; s2 += 2) {
        SCAN_STEP(s2,     Ka,  Ta,  vA0, vA1, ikA, vB0, vB1, ikB);
        SCAN_STEP(s2 + 1, Kb_, Tb_, vB0, vB1, ikB, vA0, vA1, ikA);
    }
#undef SCAN_STEP

#pragma unroll
    for (int rt = 0; rt < 4; rt++)
#pragma unroll
        for (int j = 0; j < 4; j++)
            Mfin[(size_t)bh * 4096 + (size_t)(rt * 16 + lk * 4 + j) * 64 + c0 + lr] = Mreg[rt][j];
}

// ---------------- parallel combine: A_mem from snapshots, beta-blend with A_dot ----------------
__global__ __launch_bounds__(256) void combine_kernel(const bf16_t* __restrict__ Qb,
                                                      const bf16_t* __restrict__ Msnap,
                                                      const bf16_t* __restrict__ Adot,
                                                      const float* __restrict__ invq,
                                                      const float* __restrict__ beta_param,
                                                      bf16_t* __restrict__ Op) {
    __shared__ bf16_t oS[64 * 72];
    __shared__ bf16_t adS[64 * 72];
    __shared__ float  iq[64];

    int u = blockIdx.x;
    int bh = u >> 6, s = u & 63;
    int b = bh >> 4, h = bh & 15;
    int tid = threadIdx.x;
    int w = tid >> 6, lane = tid & 63;
    int lr = lane & 15, lk = lane >> 4;
    int r = tid >> 2, c0 = (tid & 3) << 4;

    size_t vseg = ((size_t)b * 4096 + s * 64) * 1024 + (size_t)h * 64;
    size_t sb = ((size_t)bh * 64 + s) * 4096;
    size_t ib = ((size_t)bh * 64 + s) * 64;

    float beta = 1.f / (1.f + __expf(-beta_param[h]));
    float omb = 1.f - beta;

    *reinterpret_cast<bf16x8*>(&adS[r * 72 + c0]) =
        *reinterpret_cast<const bf16x8*>(Adot + sb + (size_t)r * 64 + c0);
    *reinterpret_cast<bf16x8*>(&adS[r * 72 + c0 + 8]) =
        *reinterpret_cast<const bf16x8*>(Adot + sb + (size_t)r * 64 + c0 + 8);
    if (tid < 64) iq[tid] = invq[ib + tid];

    f32x4 Y[4];
#pragma unroll
    for (int ct = 0; ct < 4; ct++) Y[ct] = (f32x4){0.f, 0.f, 0.f, 0.f};
    if (s > 0) {
        bf16x8 aq[2];
#pragma unroll
        for (int ks = 0; ks < 2; ks++)
            aq[ks] = sigma8(*reinterpret_cast<const bf16x8*>(
                Qb + vseg + (size_t)(w * 16 + lr) * 1024 + lk * 8 + ks * 32));
#pragma unroll
        for (int ct = 0; ct < 4; ct++)
#pragma unroll
            for (int ks = 0; ks < 2; ks++) {
                bf16x8 bfrag = *reinterpret_cast<const bf16x8*>(
                    Msnap + sb + (size_t)(ct * 16 + lr) * 64 + lk * 8 + ks * 32);
                Y[ct] = __builtin_amdgcn_mfma_f32_16x16x32_bf16(aq[ks], bfrag, Y[ct], 0, 0, 0);
            }
    }
    __syncthreads();

#pragma unroll
    for (int ct = 0; ct < 4; ct++) {
        int colc = ct * 16 + lr;
#pragma unroll
        for (int j = 0; j < 4; j++) {
            int t = w * 16 + lk * 4 + j;
            float o = beta * (Y[ct][j] * iq[t]) + omb * (float)adS[t * 72 + colc];
            oS[t * 72 + colc] = (bf16_t)o;
        }
    }
    __syncthreads();

    *reinterpret_cast<bf16x8*>(Op + vseg + (size_t)r * 1024 + c0) =
        *reinterpret_cast<const bf16x8*>(&oS[r * 72 + c0]);
    *reinterpret_cast<bf16x8*>(Op + vseg + (size_t)r * 1024 + c0 + 8) =
        *reinterpret_cast<const bf16x8*>(&oS[r * 72 + c0 + 8]);
}

// ---------------- final means over batch ----------------
__global__ __launch_bounds__(256) void mean_kernel(const float* __restrict__ Mfin,
                                                   const float* __restrict__ zfin,
                                                   float* __restrict__ out) {
    int idx = blockIdx.x * 256 + threadIdx.x;
    if (idx < 65536) {
        out[16777216 + idx] = 0.25f * (Mfin[idx] + Mfin[idx + 65536] +
                                       Mfin[idx + 131072] + Mfin[idx + 196608]);
    } else if (idx < 66560) {
        int j = idx - 65536;
        out[16842752 + j] = 0.25f * (zfin[j] + zfin[j + 1024] + zfin[j + 2048] + zfin[j + 3072]);
    }
}

extern "C" void kernel_launch(void* const* d_in, const int* in_sizes, int n_in,
                              void* d_out, int out_size, void* d_ws, size_t ws_size,
                              hipStream_t stream) {
    const float* x      = (const float*)d_in[0];
    const float* Wq     = (const float*)d_in[1];
    const float* Wk     = (const float*)d_in[2];
    const float* Wv     = (const float*)d_in[3];
    const float* Wo     = (const float*)d_in[4];
    const float* beta_p = (const float*)d_in[5];
    float* out = (float*)d_out;
    char* ws = (char*)d_ws;

    const size_t NX = 16777216ull;
    const size_t NW = 1048576ull;

    bf16_t* xb   = (bf16_t*)ws;
    bf16_t* Adot = xb;                                  // alias (xb dead after QKV GEMMs)
    bf16_t* Wqb  = (bf16_t*)(ws + 33554432);
    bf16_t* Wkb  = (bf16_t*)(ws + 35651584);
    bf16_t* Wvb  = (bf16_t*)(ws + 37748736);
    bf16_t* Wob  = (bf16_t*)(ws + 39845888);
    bf16_t* Qb   = (bf16_t*)(ws + 41943040);
    bf16_t* Kb   = (bf16_t*)(ws + 75497472);            // becomes sigma(k) after attn
    bf16_t* Vb   = (bf16_t*)(ws + 109051904);           // becomes v^T after attn
    bf16_t* skT  = (bf16_t*)(ws + 142606336);
    bf16_t* Op   = (bf16_t*)(ws + 176160768);
    float*  csum = (float*)(ws + 209715200);
    float*  zx   = (float*)(ws + 210763776);
    float*  invq = (float*)(ws + 211812352);
    float*  invk = (float*)(ws + 212860928);
    float*  Mfin = (float*)(ws + 213909504);
    float*  zfin = (float*)(ws + 214958080);
    bf16_t* Msnap = (bf16_t*)d_out;                     // first 33.5MB of d_out (dead until O-GEMM)

    cast_bf16_kernel<<<dim3(16384), dim3(256), 0, stream>>>(x, xb, (int)(NX / 4));
    cast_bf16_kernel<<<dim3(1024), dim3(256), 0, stream>>>(Wq, Wqb, (int)(NW / 4));
    cast_bf16_kernel<<<dim3(1024), dim3(256), 0, stream>>>(Wk, Wkb, (int)(NW / 4));
    cast_bf16_kernel<<<dim3(1024), dim3(256), 0, stream>>>(Wv, Wvb, (int)(NW / 4));
    cast_bf16_kernel<<<dim3(1024), dim3(256), 0, stream>>>(Wo, Wob, (int)(NW / 4));

    gemm256<1><<<dim3(256), dim3(512), 0, stream>>>(xb, Wqb, (void*)Qb, 16384, 1024, 1024);
    gemm256<1><<<dim3(256), dim3(512), 0, stream>>>(xb, Wkb, (void*)Kb, 16384, 1024, 1024);
    gemm256<1><<<dim3(256), dim3(512), 0, stream>>>(xb, Wvb, (void*)Vb, 16384, 1024, 1024);

    attn_kernel<<<dim3(4096), dim3(256), 0, stream>>>(Qb, Kb, Vb, skT, csum, Adot);
    zprefix_kernel<<<dim3(64), dim3(64), 0, stream>>>(csum, zx, zfin);
    denom_kernel<<<dim3(4096), dim3(128), 0, stream>>>(Qb, Kb, zx, invq, invk);
    scan_kernel<<<dim3(256), dim3(64), 0, stream>>>(Kb, Vb, skT, invk, Msnap, Mfin);
    combine_kernel<<<dim3(4096), dim3(256), 0, stream>>>(Qb, Msnap, Adot, invq, beta_p, Op);

    gemm256<0><<<dim3(256), dim3(512), 0, stream>>>(Op, Wob, d_out, 16384, 1024, 1024);
    mean_kernel<<<dim3(260), dim3(256), 0, stream>>>(Mfin, zfin, out);
}

// Round 7
// 347.159 us; speedup vs baseline: 18.3611x; 1.1625x over previous
//
#include <hip/hip_runtime.h>

typedef __bf16 bf16_t;
typedef __bf16 bf16x8 __attribute__((ext_vector_type(8)));
typedef __bf16 bf16x4 __attribute__((ext_vector_type(4)));
typedef float  f32x4  __attribute__((ext_vector_type(4)));

__device__ __forceinline__ void gload16(const bf16_t* g, bf16_t* l) {
    __builtin_amdgcn_global_load_lds(
        (const __attribute__((address_space(1))) void*)(g),
        (__attribute__((address_space(3))) void*)(l), 16, 0, 0);
}

// ---------------- f32 -> bf16 cast ----------------
__global__ __launch_bounds__(256) void cast_bf16_kernel(const float* __restrict__ in,
                                                        bf16_t* __restrict__ out, int n4) {
    int i = blockIdx.x * 256 + threadIdx.x;
    if (i >= n4) return;
    f32x4 v = *reinterpret_cast<const f32x4*>(in + (size_t)i * 4);
    bf16x4 o;
    o[0] = (bf16_t)v[0]; o[1] = (bf16_t)v[1]; o[2] = (bf16_t)v[2]; o[3] = (bf16_t)v[3];
    *reinterpret_cast<bf16x4*>(out + (size_t)i * 4) = o;
}

__device__ __forceinline__ bf16x8 sigma8(bf16x8 x) {
    bf16x8 o;
#pragma unroll
    for (int j = 0; j < 8; j++) {
        float f = (float)x[j];
        float sg = f > 0.f ? f + 1.f : __expf(f);
        o[j] = (bf16_t)sg;
    }
    return o;
}

// ---------------- 256x256 GEMM, BK=32, 4-slot LDS ring, 1 barrier + counted vmcnt ----------------
// C = A (MxK) * B^T (B is NxK row-major). 512 threads = 8 waves (2m x 4n).
template <int OUT_BF16>
__global__ __launch_bounds__(512, 2) void gemm256(const bf16_t* __restrict__ A,
                                                  const bf16_t* __restrict__ Bm,
                                                  void* __restrict__ Cv,
                                                  int M, int N, int K) {
    __shared__ bf16_t As[4][256 * 32];
    __shared__ bf16_t Bs[4][256 * 32];

    // XCD-aware mapping: XCD x covers bm in [x*8, x*8+8) so A-panels L2-hit per XCD.
    int bid = blockIdx.x;
    int xq = bid & 7, jq = bid >> 3;
    int bm = xq * 8 + (jq >> 2), bn = jq & 3;

    int tid = threadIdx.x;
    int w = tid >> 6, lane = tid & 63;
    int wm = w >> 2, wn = w & 3;
    int lr = lane & 15, lk = lane >> 4;

    // ---- staging addressing (pre-swizzled global source, linear LDS dest) ----
    int srow = lane >> 2;                      // 0..15 within a 16-row call
    int schunk = (lane & 3) ^ (srow & 3);      // logical 8-elem chunk
    const bf16_t* gA0 = A  + (size_t)(bm * 256 + w * 32 + srow) * K + schunk * 8;
    const bf16_t* gA1 = gA0 + (size_t)16 * K;
    const bf16_t* gB0 = Bm + (size_t)(bn * 256 + w * 32 + srow) * K + schunk * 8;
    const bf16_t* gB1 = gB0 + (size_t)16 * K;
    int lO0 = (w * 32) * 32 + lane * 8;        // element offset in slot
    int lO1 = (w * 32 + 16) * 32 + lane * 8;

    // ---- fragment read byte offsets (swizzled) ----
    int chunkb = (lk ^ (lr & 3)) << 4;
    int aoff[8], boff[4];
#pragma unroll
    for (int mi = 0; mi < 8; mi++) aoff[mi] = (wm * 128 + mi * 16 + lr) * 64 + chunkb;
#pragma unroll
    for (int ni = 0; ni < 4; ni++) boff[ni] = (wn * 64 + ni * 16 + lr) * 64 + chunkb;

    f32x4 acc[8][4];
#pragma unroll
    for (int mi = 0; mi < 8; mi++)
#pragma unroll
        for (int ni = 0; ni < 4; ni++) acc[mi][ni] = (f32x4){0.f, 0.f, 0.f, 0.f};

    const int NT = K >> 5;

    auto STAGE = [&](int t) {
        int slot = t & 3;
        size_t ko = (size_t)t * 32;
        gload16(gA0 + ko, &As[slot][lO0]);
        gload16(gA1 + ko, &As[slot][lO1]);
        gload16(gB0 + ko, &Bs[slot][lO0]);
        gload16(gB1 + ko, &Bs[slot][lO1]);
    };

    // prologue: stage tiles 0..2 (12 loads in flight per wave)
    STAGE(0); STAGE(1); STAGE(2);

#pragma unroll 1
    for (int t = 0; t < NT; ++t) {
        // wait for tile t only; keep tiles t+1, t+2 in flight (never drain to 0)
        int ahead = NT - 1 - t;
        if (ahead >= 2)      asm volatile("s_waitcnt vmcnt(8)" ::: "memory");
        else if (ahead == 1) asm volatile("s_waitcnt vmcnt(4)" ::: "memory");
        else                 asm volatile("s_waitcnt vmcnt(0)" ::: "memory");
        __builtin_amdgcn_sched_barrier(0);
        __builtin_amdgcn_s_barrier();   // all waves' tile-t loads landed; prev slot reads done
        __builtin_amdgcn_sched_barrier(0);

        const char* pa = (const char*)(&As[t & 3][0]);
        const char* pb = (const char*)(&Bs[t & 3][0]);
        bf16x8 af[8], bfr[4];
#pragma unroll
        for (int mi = 0; mi < 8; mi++)
            af[mi] = *reinterpret_cast<const bf16x8*>(pa + aoff[mi]);
#pragma unroll
        for (int ni = 0; ni < 4; ni++)
            bfr[ni] = *reinterpret_cast<const bf16x8*>(pb + boff[ni]);

        if (t + 3 < NT) STAGE(t + 3);   // overwrites slot (t-1)&3 -- safe after barrier

        asm volatile("s_waitcnt lgkmcnt(0)" ::: "memory");
        __builtin_amdgcn_sched_barrier(0);
        __builtin_amdgcn_s_setprio(1);
#pragma unroll
        for (int mi = 0; mi < 8; mi++)
#pragma unroll
            for (int ni = 0; ni < 4; ni++)
                acc[mi][ni] = __builtin_amdgcn_mfma_f32_16x16x32_bf16(af[mi], bfr[ni], acc[mi][ni], 0, 0, 0);
        __builtin_amdgcn_s_setprio(0);
    }

    int row0 = bm * 256 + wm * 128 + lk * 4;
    int col0 = bn * 256 + wn * 64 + lr;
#pragma unroll
    for (int mi = 0; mi < 8; mi++)
#pragma unroll
        for (int ni = 0; ni < 4; ni++)
#pragma unroll
            for (int jj = 0; jj < 4; jj++) {
                size_t idx = (size_t)(row0 + mi * 16 + jj) * N + (col0 + ni * 16);
                float v = acc[mi][ni][jj];
                if (OUT_BF16) reinterpret_cast<bf16_t*>(Cv)[idx] = (bf16_t)v;
                else          reinterpret_cast<float*>(Cv)[idx]  = v;
            }
}

// ---------------- parallel local attention; writes sigma(k) in place over Kb,
// v^T in place over Vb, sigma(k)^T dense, column sums, A_dot ----------------
__global__ __launch_bounds__(256) void attn_kernel(const bf16_t* __restrict__ Qb,
                                                   bf16_t* __restrict__ Kb,
                                                   bf16_t* __restrict__ Vb,
                                                   bf16_t* __restrict__ skTg,
                                                   float* __restrict__ csum,
                                                   bf16_t* __restrict__ Adot) {
    __shared__ bf16_t kS[64 * 72];
    __shared__ bf16_t vS[64 * 72];
    __shared__ bf16_t skT[64 * 72];
    __shared__ bf16_t vT[64 * 72];
    __shared__ bf16_t pS[64 * 72];
    __shared__ float  scr[64 * 68];

    int u = blockIdx.x;
    int bh = u >> 6, s = u & 63;
    int b = bh >> 4, h = bh & 15;
    int tid = threadIdx.x;
    int w = tid >> 6, lane = tid & 63;
    int lr = lane & 15, lk = lane >> 4;
    int r = tid >> 2, qd = tid & 3, c0 = qd << 4;

    size_t vseg = ((size_t)b * 4096 + s * 64) * 1024 + (size_t)h * 64;
    size_t sb = ((size_t)bh * 64 + s) * 4096;

    {
        bf16x8 k0 = *reinterpret_cast<const bf16x8*>(Kb + vseg + (size_t)r * 1024 + c0);
        bf16x8 k1 = *reinterpret_cast<const bf16x8*>(Kb + vseg + (size_t)r * 1024 + c0 + 8);
        bf16x8 v0 = *reinterpret_cast<const bf16x8*>(Vb + vseg + (size_t)r * 1024 + c0);
        bf16x8 v1 = *reinterpret_cast<const bf16x8*>(Vb + vseg + (size_t)r * 1024 + c0 + 8);
        *reinterpret_cast<bf16x8*>(&kS[r * 72 + c0])     = k0;
        *reinterpret_cast<bf16x8*>(&kS[r * 72 + c0 + 8]) = k1;
        *reinterpret_cast<bf16x8*>(&vS[r * 72 + c0])     = v0;
        *reinterpret_cast<bf16x8*>(&vS[r * 72 + c0 + 8]) = v1;
        bf16x8 s0 = sigma8(k0), s1 = sigma8(k1);
        *reinterpret_cast<bf16x8*>(Kb + vseg + (size_t)r * 1024 + c0)     = s0;
        *reinterpret_cast<bf16x8*>(Kb + vseg + (size_t)r * 1024 + c0 + 8) = s1;
#pragma unroll
        for (int j = 0; j < 8; j++) {
            skT[(c0 + j) * 72 + r]     = s0[j];
            skT[(c0 + 8 + j) * 72 + r] = s1[j];
            vT[(c0 + j) * 72 + r]      = v0[j];
            vT[(c0 + 8 + j) * 72 + r]  = v1[j];
        }
    }
    __syncthreads();

    if (tid < 64) {
        float acc = 0.f;
#pragma unroll 8
        for (int t = 0; t < 64; t++) acc += (float)skT[tid * 72 + t];
        csum[((size_t)bh * 64 + s) * 64 + tid] = acc;
    }
    *reinterpret_cast<bf16x8*>(skTg + sb + (size_t)r * 64 + c0) =
        *reinterpret_cast<const bf16x8*>(&skT[r * 72 + c0]);
    *reinterpret_cast<bf16x8*>(skTg + sb + (size_t)r * 64 + c0 + 8) =
        *reinterpret_cast<const bf16x8*>(&skT[r * 72 + c0 + 8]);
    *reinterpret_cast<bf16x8*>(Vb + vseg + (size_t)r * 1024 + c0) =
        *reinterpret_cast<const bf16x8*>(&vT[r * 72 + c0]);
    *reinterpret_cast<bf16x8*>(Vb + vseg + (size_t)r * 1024 + c0 + 8) =
        *reinterpret_cast<const bf16x8*>(&vT[r * 72 + c0 + 8]);

    {
        bf16x8 aq[2];
#pragma unroll
        for (int ks = 0; ks < 2; ks++)
            aq[ks] = *reinterpret_cast<const bf16x8*>(Qb + vseg + (size_t)(w * 16 + lr) * 1024 + lk * 8 + ks * 32);
        f32x4 sc[4];
#pragma unroll
        for (int ct = 0; ct < 4; ct++) {
            sc[ct] = (f32x4){0.f, 0.f, 0.f, 0.f};
#pragma unroll
            for (int ks = 0; ks < 2; ks++) {
                bf16x8 bfrag = *reinterpret_cast<const bf16x8*>(&kS[(ct * 16 + lr) * 72 + lk * 8 + ks * 32]);
                sc[ct] = __builtin_amdgcn_mfma_f32_16x16x32_bf16(aq[ks], bfrag, sc[ct], 0, 0, 0);
            }
        }
#pragma unroll
        for (int ct = 0; ct < 4; ct++)
#pragma unroll
            for (int j = 0; j < 4; j++)
                scr[(w * 16 + lk * 4 + j) * 68 + ct * 16 + lr] = sc[ct][j] * 0.125f;
    }
    __syncthreads();

    {
        float p[16];
        float mx = -3.4e38f;
        const float* srow_p = &scr[r * 68 + c0];
#pragma unroll
        for (int i = 0; i < 16; i++) {
            int c = c0 + i;
            float v = (c <= r) ? srow_p[i] : -3.4e38f;
            p[i] = v;
            mx = fmaxf(mx, v);
        }
        mx = fmaxf(mx, __shfl_xor(mx, 1));
        mx = fmaxf(mx, __shfl_xor(mx, 2));
        float sum = 0.f;
#pragma unroll
        for (int i = 0; i < 16; i++) {
            int c = c0 + i;
            float e = (c <= r) ? __expf(p[i] - mx) : 0.f;
            p[i] = e;
            sum += e;
        }
        sum += __shfl_xor(sum, 1);
        sum += __shfl_xor(sum, 2);
        float inv = 1.f / sum;
        bf16x8 p0, p1;
#pragma unroll
        for (int j = 0; j < 8; j++) {
            p0[j] = (bf16_t)(p[j] * inv);
            p1[j] = (bf16_t)(p[8 + j] * inv);
        }
        *reinterpret_cast<bf16x8*>(&pS[r * 72 + c0])     = p0;
        *reinterpret_cast<bf16x8*>(&pS[r * 72 + c0 + 8]) = p1;
    }
    __syncthreads();

    {
        f32x4 ad[4];
#pragma unroll
        for (int ct = 0; ct < 4; ct++) {
            ad[ct] = (f32x4){0.f, 0.f, 0.f, 0.f};
#pragma unroll
            for (int ks = 0; ks < 2; ks++) {
                bf16x8 afrag = *reinterpret_cast<const bf16x8*>(&pS[(w * 16 + lr) * 72 + lk * 8 + ks * 32]);
                bf16x8 bfrag = *reinterpret_cast<const bf16x8*>(&vT[(ct * 16 + lr) * 72 + lk * 8 + ks * 32]);
                ad[ct] = __builtin_amdgcn_mfma_f32_16x16x32_bf16(afrag, bfrag, ad[ct], 0, 0, 0);
            }
        }
#pragma unroll
        for (int ct = 0; ct < 4; ct++)
#pragma unroll
            for (int j = 0; j < 4; j++)
                kS[(w * 16 + lk * 4 + j) * 72 + ct * 16 + lr] = (bf16_t)ad[ct][j];
    }
    __syncthreads();
    *reinterpret_cast<bf16x8*>(Adot + sb + (size_t)r * 64 + c0) =
        *reinterpret_cast<const bf16x8*>(&kS[r * 72 + c0]);
    *reinterpret_cast<bf16x8*>(Adot + sb + (size_t)r * 64 + c0 + 8) =
        *reinterpret_cast<const bf16x8*>(&kS[r * 72 + c0 + 8]);
}

// ---------------- z prefix over segments ----------------
__global__ __launch_bounds__(64) void zprefix_kernel(const float* __restrict__ csum,
                                                     float* __restrict__ zx,
                                                     float* __restrict__ zfin) {
    int bh = blockIdx.x;
    int d = threadIdx.x;
    float z = 0.f;
    for (int s = 0; s < 64; s++) {
        size_t o = ((size_t)bh * 64 + s) * 64 + d;
        zx[o] = z;
        z += csum[o];
    }
    zfin[bh * 64 + d] = z;
}

// ---------------- denominators 1/(sigma . z + eps) ----------------
__global__ __launch_bounds__(128) void denom_kernel(const bf16_t* __restrict__ Qb,
                                                    const bf16_t* __restrict__ sK,
                                                    const float* __restrict__ zx,
                                                    float* __restrict__ invq,
                                                    float* __restrict__ invk) {
    __shared__ float zL[64];
    int u = blockIdx.x;
    int bh = u >> 6, s = u & 63;
    int b = bh >> 4, h = bh & 15;
    int tid = threadIdx.x;
    if (tid < 64) zL[tid] = zx[((size_t)bh * 64 + s) * 64 + tid];
    __syncthreads();
    int row = tid & 63;
    bool isq = tid < 64;
    const bf16_t* src = (isq ? Qb : sK) +
                        ((size_t)b * 4096 + s * 64 + row) * 1024 + (size_t)h * 64;
    float acc = 0.f;
#pragma unroll
    for (int blk = 0; blk < 8; blk++) {
        bf16x8 v = *reinterpret_cast<const bf16x8*>(src + blk * 8);
#pragma unroll
        for (int j = 0; j < 8; j++) {
            float f = (float)v[j];
            float sg;
            if (isq) {
                sg = f > 0.f ? f + 1.f : __expf(f);
                sg = (float)(bf16_t)sg;
            } else {
                sg = f;
            }
            acc = __builtin_fmaf(sg, zL[blk * 8 + j], acc);
        }
    }
    float inv = 1.f / (acc + 1e-6f);
    float* dst = isq ? invq : invk;
    dst[((size_t)bh * 64 + s) * 64 + row] = inv;
}

// ---------------- k-side recurrence scan: 1 wave per block, no barriers, depth-1 prefetch ----
// grid 256: bh = blk & 63, cq = blk >> 6 (column quarter). M cols c0..c0+15 per block.
__global__ __launch_bounds__(64, 1) void scan_kernel(const bf16_t* __restrict__ sK,
                                                     const bf16_t* __restrict__ vTg,
                                                     const bf16_t* __restrict__ skTg,
                                                     const float* __restrict__ invk,
                                                     bf16_t* __restrict__ Msnap,
                                                     float* __restrict__ Mfin) {
    __shared__ bf16_t MbL[16 * 72];  // M^T slice: row = local col, elems = M row (swizzled)
    __shared__ bf16_t uTL[16 * 72];  // v^T slice -> u^T in place (swizzled)
    __shared__ float  ikL[64];

    int blk = blockIdx.x;
    int bh = blk & 63, cq = blk >> 6;
    int c0 = cq << 4;
    int b = bh >> 4, h = bh & 15;
    int lane = threadIdx.x;
    int lr = lane & 15, lk = lane >> 4;
    int vr = lane >> 2, vt0 = (lane & 3) << 4;

    size_t chbase = ((size_t)b * 4096) * 1024 + (size_t)h * 64;
    size_t stbase = (size_t)bh * 64 * 4096;

    auto swz = [](bf16_t* base, int row, int intra) -> bf16_t* {
        return (bf16_t*)((char*)base + row * 144 + (intra ^ ((row & 7) << 4)));
    };

    for (int i = lane; i < 16 * 72; i += 64) MbL[i] = (bf16_t)0.f;
    f32x4 Mreg[4];
#pragma unroll
    for (int rt = 0; rt < 4; rt++) Mreg[rt] = (f32x4){0.f, 0.f, 0.f, 0.f};

    bf16x8 cK[4][2], cT[4][2];
#pragma unroll
    for (int rt = 0; rt < 4; rt++)
#pragma unroll
        for (int ks = 0; ks < 2; ks++) {
            cK[rt][ks] = *reinterpret_cast<const bf16x8*>(
                sK + chbase + (size_t)(rt * 16 + lr) * 1024 + lk * 8 + ks * 32);
            cT[rt][ks] = *reinterpret_cast<const bf16x8*>(
                skTg + stbase + (size_t)(rt * 16 + lr) * 64 + lk * 8 + ks * 32);
        }
    {
        bf16x8 v0 = *reinterpret_cast<const bf16x8*>(vTg + chbase + (size_t)(c0 + vr) * 1024 + vt0);
        bf16x8 v1 = *reinterpret_cast<const bf16x8*>(vTg + chbase + (size_t)(c0 + vr) * 1024 + vt0 + 8);
        *reinterpret_cast<bf16x8*>(swz(uTL, vr, vt0 * 2))      = v0;
        *reinterpret_cast<bf16x8*>(swz(uTL, vr, vt0 * 2 + 16)) = v1;
        ikL[lane] = invk[(size_t)bh * 4096 + lane];
    }

    for (int s = 0; s < 64; s++) {
        bf16x8 nK[4][2], nT[4][2], nv0, nv1;
        float nik = 0.f;
        if (s < 63) {
            size_t vs2 = chbase + (size_t)(s + 1) * 65536;
            size_t sb2 = stbase + (size_t)(s + 1) * 4096;
#pragma unroll
            for (int rt = 0; rt < 4; rt++)
#pragma unroll
                for (int ks = 0; ks < 2; ks++) {
                    nK[rt][ks] = *reinterpret_cast<const bf16x8*>(
                        sK + vs2 + (size_t)(rt * 16 + lr) * 1024 + lk * 8 + ks * 32);
                    nT[rt][ks] = *reinterpret_cast<const bf16x8*>(
                        skTg + sb2 + (size_t)(rt * 16 + lr) * 64 + lk * 8 + ks * 32);
                }
            nv0 = *reinterpret_cast<const bf16x8*>(vTg + vs2 + (size_t)(c0 + vr) * 1024 + vt0);
            nv1 = *reinterpret_cast<const bf16x8*>(vTg + vs2 + (size_t)(c0 + vr) * 1024 + vt0 + 8);
            nik = invk[(size_t)bh * 4096 + (size_t)(s + 1) * 64 + lane];
        }

        // MFMA1: Y = sigma(k) @ M[:, c0:c0+16]
        bf16x8 mb0 = *reinterpret_cast<const bf16x8*>(swz(MbL, lr, lk * 16));
        bf16x8 mb1 = *reinterpret_cast<const bf16x8*>(swz(MbL, lr, lk * 16 + 64));
        f32x4 Y[4];
#pragma unroll
        for (int rt = 0; rt < 4; rt++) {
            Y[rt] = (f32x4){0.f, 0.f, 0.f, 0.f};
            Y[rt] = __builtin_amdgcn_mfma_f32_16x16x32_bf16(cK[rt][0], mb0, Y[rt], 0, 0, 0);
            Y[rt] = __builtin_amdgcn_mfma_f32_16x16x32_bf16(cK[rt][1], mb1, Y[rt], 0, 0, 0);
        }

        // epilogue: u = v - Y*invk[t], in place in uTL
#pragma unroll
        for (int rt = 0; rt < 4; rt++) {
            bf16x4 vv = *reinterpret_cast<const bf16x4*>(swz(uTL, lr, rt * 32 + lk * 8));
            bf16x4 uu;
#pragma unroll
            for (int j = 0; j < 4; j++) {
                float ik = ikL[rt * 16 + lk * 4 + j];
                uu[j] = (bf16_t)((float)vv[j] - Y[rt][j] * ik);
            }
            *reinterpret_cast<bf16x4*>(swz(uTL, lr, rt * 32 + lk * 8)) = uu;
        }

        // MFMA2: M[:, c0:+16] += sigma(k)^T @ u
        bf16x8 ub0 = *reinterpret_cast<const bf16x8*>(swz(uTL, lr, lk * 16));
        bf16x8 ub1 = *reinterpret_cast<const bf16x8*>(swz(uTL, lr, lk * 16 + 64));
#pragma unroll
        for (int rt = 0; rt < 4; rt++) {
            Mreg[rt] = __builtin_amdgcn_mfma_f32_16x16x32_bf16(cT[rt][0], ub0, Mreg[rt], 0, 0, 0);
            Mreg[rt] = __builtin_amdgcn_mfma_f32_16x16x32_bf16(cT[rt][1], ub1, Mreg[rt], 0, 0, 0);
        }

        // refresh bf16 M^T slice + snapshot store (M_{s+1}, consumed by combine at seg s+1)
#pragma unroll
        for (int rt = 0; rt < 4; rt++) {
            bf16x4 mp;
#pragma unroll
            for (int j = 0; j < 4; j++) mp[j] = (bf16_t)Mreg[rt][j];
            *reinterpret_cast<bf16x4*>(swz(MbL, lr, rt * 32 + lk * 8)) = mp;
            if (s < 63)
                *reinterpret_cast<bf16x4*>(
                    Msnap + (((size_t)bh * 64 + s + 1) * 64 + c0 + lr) * 64 + rt * 16 + lk * 4) = mp;
        }

        if (s < 63) {
#pragma unroll
            for (int rt = 0; rt < 4; rt++)
#pragma unroll
                for (int ks = 0; ks < 2; ks++) { cK[rt][ks] = nK[rt][ks]; cT[rt][ks] = nT[rt][ks]; }
            *reinterpret_cast<bf16x8*>(swz(uTL, vr, vt0 * 2))      = nv0;
            *reinterpret_cast<bf16x8*>(swz(uTL, vr, vt0 * 2 + 16)) = nv1;
            ikL[lane] = nik;
        }
    }

    // final M slice (f32)
#pragma unroll
    for (int rt = 0; rt < 4; rt++)
#pragma unroll
        for (int j = 0; j < 4; j++)
            Mfin[(size_t)bh * 4096 + (size_t)(rt * 16 + lk * 4 + j) * 64 + c0 + lr] = Mreg[rt][j];
}

// ---------------- parallel combine: A_mem from snapshots, beta-blend with A_dot ----------------
__global__ __launch_bounds__(256) void combine_kernel(const bf16_t* __restrict__ Qb,
                                                      const bf16_t* __restrict__ Msnap,
                                                      const bf16_t* __restrict__ Adot,
                                                      const float* __restrict__ invq,
                                                      const float* __restrict__ beta_param,
                                                      bf16_t* __restrict__ Op) {
    __shared__ bf16_t oS[64 * 72];
    __shared__ bf16_t adS[64 * 72];
    __shared__ float  iq[64];

    int u = blockIdx.x;
    int bh = u >> 6, s = u & 63;
    int b = bh >> 4, h = bh & 15;
    int tid = threadIdx.x;
    int w = tid >> 6, lane = tid & 63;
    int lr = lane & 15, lk = lane >> 4;
    int r = tid >> 2, c0 = (tid & 3) << 4;

    size_t vseg = ((size_t)b * 4096 + s * 64) * 1024 + (size_t)h * 64;
    size_t sb = ((size_t)bh * 64 + s) * 4096;
    size_t ib = ((size_t)bh * 64 + s) * 64;

    float beta = 1.f / (1.f + __expf(-beta_param[h]));
    float omb = 1.f - beta;

    *reinterpret_cast<bf16x8*>(&adS[r * 72 + c0]) =
        *reinterpret_cast<const bf16x8*>(Adot + sb + (size_t)r * 64 + c0);
    *reinterpret_cast<bf16x8*>(&adS[r * 72 + c0 + 8]) =
        *reinterpret_cast<const bf16x8*>(Adot + sb + (size_t)r * 64 + c0 + 8);
    if (tid < 64) iq[tid] = invq[ib + tid];

    f32x4 Y[4];
#pragma unroll
    for (int ct = 0; ct < 4; ct++) Y[ct] = (f32x4){0.f, 0.f, 0.f, 0.f};
    if (s > 0) {
        bf16x8 aq[2];
#pragma unroll
        for (int ks = 0; ks < 2; ks++)
            aq[ks] = sigma8(*reinterpret_cast<const bf16x8*>(
                Qb + vseg + (size_t)(w * 16 + lr) * 1024 + lk * 8 + ks * 32));
#pragma unroll
        for (int ct = 0; ct < 4; ct++)
#pragma unroll
            for (int ks = 0; ks < 2; ks++) {
                bf16x8 bfrag = *reinterpret_cast<const bf16x8*>(
                    Msnap + sb + (size_t)(ct * 16 + lr) * 64 + lk * 8 + ks * 32);
                Y[ct] = __builtin_amdgcn_mfma_f32_16x16x32_bf16(aq[ks], bfrag, Y[ct], 0, 0, 0);
            }
    }
    __syncthreads();

#pragma unroll
    for (int ct = 0; ct < 4; ct++) {
        int colc = ct * 16 + lr;
#pragma unroll
        for (int j = 0; j < 4; j++) {
            int t = w * 16 + lk * 4 + j;
            float o = beta * (Y[ct][j] * iq[t]) + omb * (float)adS[t * 72 + colc];
            oS[t * 72 + colc] = (bf16_t)o;
        }
    }
    __syncthreads();

    *reinterpret_cast<bf16x8*>(Op + vseg + (size_t)r * 1024 + c0) =
        *reinterpret_cast<const bf16x8*>(&oS[r * 72 + c0]);
    *reinterpret_cast<bf16x8*>(Op + vseg + (size_t)r * 1024 + c0 + 8) =
        *reinterpret_cast<const bf16x8*>(&oS[r * 72 + c0 + 8]);
}

// ---------------- final means over batch ----------------
__global__ __launch_bounds__(256) void mean_kernel(const float* __restrict__ Mfin,
                                                   const float* __restrict__ zfin,
                                                   float* __restrict__ out) {
    int idx = blockIdx.x * 256 + threadIdx.x;
    if (idx < 65536) {
        out[16777216 + idx] = 0.25f * (Mfin[idx] + Mfin[idx + 65536] +
                                       Mfin[idx + 131072] + Mfin[idx + 196608]);
    } else if (idx < 66560) {
        int j = idx - 65536;
        out[16842752 + j] = 0.25f * (zfin[j] + zfin[j + 1024] + zfin[j + 2048] + zfin[j + 3072]);
    }
}

extern "C" void kernel_launch(void* const* d_in, const int* in_sizes, int n_in,
                              void* d_out, int out_size, void* d_ws, size_t ws_size,
                              hipStream_t stream) {
    const float* x      = (const float*)d_in[0];
    const float* Wq     = (const float*)d_in[1];
    const float* Wk     = (const float*)d_in[2];
    const float* Wv     = (const float*)d_in[3];
    const float* Wo     = (const float*)d_in[4];
    const float* beta_p = (const float*)d_in[5];
    float* out = (float*)d_out;
    char* ws = (char*)d_ws;

    const size_t NX = 16777216ull;
    const size_t NW = 1048576ull;

    bf16_t* xb   = (bf16_t*)ws;
    bf16_t* Adot = xb;                                  // alias (xb dead after QKV GEMMs)
    bf16_t* Wqb  = (bf16_t*)(ws + 33554432);
    bf16_t* Wkb  = (bf16_t*)(ws + 35651584);
    bf16_t* Wvb  = (bf16_t*)(ws + 37748736);
    bf16_t* Wob  = (bf16_t*)(ws + 39845888);
    bf16_t* Qb   = (bf16_t*)(ws + 41943040);
    bf16_t* Kb   = (bf16_t*)(ws + 75497472);            // becomes sigma(k) after attn
    bf16_t* Vb   = (bf16_t*)(ws + 109051904);           // becomes v^T after attn
    bf16_t* skT  = (bf16_t*)(ws + 142606336);
    bf16_t* Op   = (bf16_t*)(ws + 176160768);
    float*  csum = (float*)(ws + 209715200);
    float*  zx   = (float*)(ws + 210763776);
    float*  invq = (float*)(ws + 211812352);
    float*  invk = (float*)(ws + 212860928);
    float*  Mfin = (float*)(ws + 213909504);
    float*  zfin = (float*)(ws + 214958080);
    bf16_t* Msnap = (bf16_t*)d_out;                     // first 33.5MB of d_out (dead until O-GEMM)

    cast_bf16_kernel<<<dim3(16384), dim3(256), 0, stream>>>(x, xb, (int)(NX / 4));
    cast_bf16_kernel<<<dim3(1024), dim3(256), 0, stream>>>(Wq, Wqb, (int)(NW / 4));
    cast_bf16_kernel<<<dim3(1024), dim3(256), 0, stream>>>(Wk, Wkb, (int)(NW / 4));
    cast_bf16_kernel<<<dim3(1024), dim3(256), 0, stream>>>(Wv, Wvb, (int)(NW / 4));
    cast_bf16_kernel<<<dim3(1024), dim3(256), 0, stream>>>(Wo, Wob, (int)(NW / 4));

    gemm256<1><<<dim3(256), dim3(512), 0, stream>>>(xb, Wqb, (void*)Qb, 16384, 1024, 1024);
    gemm256<1><<<dim3(256), dim3(512), 0, stream>>>(xb, Wkb, (void*)Kb, 16384, 1024, 1024);
    gemm256<1><<<dim3(256), dim3(512), 0, stream>>>(xb, Wvb, (void*)Vb, 16384, 1024, 1024);

    attn_kernel<<<dim3(4096), dim3(256), 0, stream>>>(Qb, Kb, Vb, skT, csum, Adot);
    zprefix_kernel<<<dim3(64), dim3(64), 0, stream>>>(csum, zx, zfin);
    denom_kernel<<<dim3(4096), dim3(128), 0, stream>>>(Qb, Kb, zx, invq, invk);
    scan_kernel<<<dim3(256), dim3(64), 0, stream>>>(Kb, Vb, skT, invk, Msnap, Mfin);
    combine_kernel<<<dim3(4096), dim3(256), 0, stream>>>(Qb, Msnap, Adot, invq, beta_p, Op);

    gemm256<0><<<dim3(256), dim3(512), 0, stream>>>(Op, Wob, d_out, 16384, 1024, 1024);
    mean_kernel<<<dim3(260), dim3(256), 0, stream>>>(Mfin, zfin, out);
}